// Round 12
// baseline (608.157 us; speedup 1.0000x reference)
//
#include <hip/hip_runtime.h>

#define BB 16
#define NN 1024
#define KNN 20
#define BNEPS 1e-5f

typedef __attribute__((ext_vector_type(8))) short short8;
typedef __attribute__((ext_vector_type(4))) float f32x4;

__device__ __forceinline__ float4 ld4(const float* p){ return *(const float4*)p; }
__device__ __forceinline__ void fma4(float4& a, float s, float4 w){
  a.x = fmaf(s, w.x, a.x); a.y = fmaf(s, w.y, a.y);
  a.z = fmaf(s, w.z, a.z); a.w = fmaf(s, w.w, a.w);
}
__device__ __forceinline__ void max4(float4& a, float4 v){
  a.x = fmaxf(a.x, v.x); a.y = fmaxf(a.y, v.y);
  a.z = fmaxf(a.z, v.z); a.w = fmaxf(a.w, v.w);
}
__device__ __forceinline__ unsigned short f2bf(float f){
  unsigned int u = __float_as_uint(f);
  u = (u + 0x7FFF + ((u >> 16) & 1)) >> 16;   // RNE, finite inputs
  return (unsigned short)u;
}
__device__ __forceinline__ f32x4 mfma16(short8 a, short8 b, f32x4 c){
  return __builtin_amdgcn_mfma_f32_16x16x32_bf16(a, b, c, 0, 0, 0);
}

// DPP max step on VALU pipe (no LDS): invalid source lanes keep old value (bound_ctrl=0)
#define DPPMAX(g, ctrl) \
  g = fmaxf(g, __int_as_float(__builtin_amdgcn_update_dpp(__float_as_int(g), __float_as_int(g), ctrl, 0xf, 0xf, false)))

// ---------------- transpose x (B,3,N) -> xt (B,N,4) padded ----------------
__global__ __launch_bounds__(256) void k_transpose(const float* __restrict__ x, float* __restrict__ xt){
  int i = blockIdx.x*256 + threadIdx.x;
  if (i >= BB*NN) return;
  int b = i >> 10, n = i & 1023;
  const float* xb = x + (size_t)b*3*NN;
  float4 v;
  v.x = xb[0*NN+n]; v.y = xb[1*NN+n]; v.z = xb[2*NN+n]; v.w = 0.f;
  ((float4*)xt)[i] = v;
}

// ---- L1 prep (fp32 [c][o] layout): BN folded ----
__global__ __launch_bounds__(256) void k_prep_w(const float* __restrict__ w, const float* __restrict__ bnp,
                                                float* __restrict__ wlT, float* __restrict__ dT,
                                                float* __restrict__ bias, int Cin, int Cpad, int Cout){
  int i = blockIdx.x*256 + threadIdx.x;
  if (i >= Cpad*Cout) return;
  int c = i / Cout, o = i - c*Cout;
  float s = bnp[o] * rsqrtf(bnp[3*Cout+o] + BNEPS);
  float wl = (c < Cin) ? w[(size_t)o*2*Cin + c] : 0.f;
  float wr = (c < Cin) ? w[(size_t)o*2*Cin + Cin + c] : 0.f;
  wlT[i] = wl * s;
  dT[i]  = (wr - wl) * s;
  if (c == 0) bias[o] = bnp[Cout+o] - bnp[2*Cout+o]*s;
}

// ---- bf16 prep: wlB[o][c], dB[o][c] (row-major over c), BN folded ----
__global__ __launch_bounds__(256) void k_prep_wbf(const float* __restrict__ w, const float* __restrict__ bnp,
                                                  unsigned short* __restrict__ wlB, unsigned short* __restrict__ dB,
                                                  float* __restrict__ bias, int Cin, int Cout){
  int i = blockIdx.x*256 + threadIdx.x;
  if (i >= Cin*Cout) return;
  int o = i / Cin, c = i - o*Cin;
  float s = bnp[o] * rsqrtf(bnp[3*Cout+o] + BNEPS);
  float wl = w[(size_t)o*2*Cin + c] * s;
  float wr = w[(size_t)o*2*Cin + Cin + c] * s;
  wlB[i] = f2bf(wl);
  dB[i]  = f2bf(wr - wl);
  if (c == 0) bias[o] = bnp[Cout+o] - bnp[2*Cout+o]*s;
}

__global__ __launch_bounds__(256) void k_prep_w5b(const float* __restrict__ w5, const float* __restrict__ bn5,
                                                  unsigned short* __restrict__ w5b, float* __restrict__ b5){
  int i = blockIdx.x*256 + threadIdx.x;
  if (i >= 1024*512) return;
  int o = i >> 9, c = i & 511;
  float s = bn5[o] * rsqrtf(bn5[3*1024+o] + BNEPS);
  w5b[i] = f2bf(w5[(size_t)o*512 + c] * s);
  if (c == 0) b5[o] = bn5[1024+o] - bn5[2*1024+o]*s;
}

// ---------------- sq[b*N+n] = sum_c in[n][c]^2 ----------------
__global__ __launch_bounds__(256) void k_sq(const float* __restrict__ xin, int rs, int Cin, float* __restrict__ sq){
  int i = blockIdx.x*256 + threadIdx.x;
  if (i >= BB*NN) return;
  const float* r = xin + (size_t)i*rs;
  float s = 0.f;
  for (int c = 0; c < Cin; c += 4){
    float4 v = ld4(r + c);
    s += v.x*v.x + v.y*v.y + v.z*v.z + v.w*v.w;
  }
  sq[i] = s;
}

// -------- pd[b][n][m] = 2*dot(x_n,x_m) - sq[m]  (128x128 tile, 8x8 acc, fp32) --------
// R10 proven config: runtime CT, shift/and staging, VGPR~76, 0 conflicts, 69us
__global__ __launch_bounds__(256) void k_pd(const float* __restrict__ xin, int rs, int Cin, int CT, int lnf4,
                                            const float* __restrict__ sq, float* __restrict__ pd){
  extern __shared__ float lds[];
  const int pitch = CT + 4;
  float* As = lds;
  float* Bs = lds + 128*pitch;
  const int b = blockIdx.z;
  const int n0 = blockIdx.y*128, m0 = blockIdx.x*128;
  const int tid = threadIdx.x;
  const int tx = tid & 15, ty = tid >> 4;
  const float* xb = xin + (size_t)b*NN*rs;
  float acc[8][8];
#pragma unroll
  for (int i = 0; i < 8; i++)
#pragma unroll
    for (int j = 0; j < 8; j++) acc[i][j] = 0.f;

  const int nf4 = CT >> 2;
  for (int c0 = 0; c0 < Cin; c0 += CT){
    for (int e = tid; e < 128*nf4; e += 256){
      int r = e >> lnf4, cc = (e & (nf4-1))*4;    // shift/and, no division
      *(float4*)(As + r*pitch + cc) = ld4(xb + (size_t)(n0+r)*rs + c0 + cc);
      *(float4*)(Bs + r*pitch + cc) = ld4(xb + (size_t)(m0+r)*rs + c0 + cc);
    }
    __syncthreads();
    for (int c = 0; c < CT; c += 4){
      float4 a[8], bv[8];
#pragma unroll
      for (int i = 0; i < 8; i++) a[i]  = ld4(As + (ty+16*i)*pitch + c);
#pragma unroll
      for (int j = 0; j < 8; j++) bv[j] = ld4(Bs + (tx+16*j)*pitch + c);
#pragma unroll
      for (int i = 0; i < 8; i++)
#pragma unroll
        for (int j = 0; j < 8; j++){
          acc[i][j] = fmaf(a[i].x, bv[j].x, acc[i][j]);
          acc[i][j] = fmaf(a[i].y, bv[j].y, acc[i][j]);
          acc[i][j] = fmaf(a[i].z, bv[j].z, acc[i][j]);
          acc[i][j] = fmaf(a[i].w, bv[j].w, acc[i][j]);
        }
    }
    __syncthreads();
  }
#pragma unroll
  for (int i = 0; i < 8; i++){
    int n = n0 + ty + 16*i;
#pragma unroll
    for (int j = 0; j < 8; j++){
      int m = m0 + tx + 16*j;
      pd[((size_t)b*NN + n)*NN + m] = 2.f*acc[i][j] - sq[b*NN + m];
    }
  }
}

// ------------ top-k v4 (k=20): DPP wave-max on VALU pipe (no LDS bpermute), ballot owner ------------
// tie semantics match jax.lax.top_k: value desc, index asc
__global__ __launch_bounds__(256) void k_topk(const float* __restrict__ pd, int* __restrict__ idxOut){
  int w = threadIdx.x >> 6, lane = threadIdx.x & 63;
  int bn0 = (blockIdx.x*4 + w)*2;
  float vv[2][16];
  float lmax[2];
#pragma unroll
  for (int rr = 0; rr < 2; rr++){
    const float* row = pd + (size_t)(bn0+rr)*NN;
#pragma unroll
    for (int r = 0; r < 4; r++){
      float4 t = ld4(row + lane*16 + r*4);
      vv[rr][r*4+0] = t.x; vv[rr][r*4+1] = t.y; vv[rr][r*4+2] = t.z; vv[rr][r*4+3] = t.w;
    }
    float m = vv[rr][0];
#pragma unroll
    for (int e = 1; e < 16; e++) m = fmaxf(m, vv[rr][e]);
    lmax[rr] = m;
  }

  int* out0 = idxOut + (size_t)bn0*KNN;
  int* out1 = out0 + KNN;
  for (int it = 0; it < KNN; it++){
    // wave-global max via DPP (row_shr 1,2,4,8 -> row max in lane15 of each row;
    // bcast15 merges r0->r1 / r2->r3; bcast31 merges halves; lane 63 = global)
    float g0 = lmax[0], g1 = lmax[1];
    DPPMAX(g0,0x111); DPPMAX(g1,0x111);
    DPPMAX(g0,0x112); DPPMAX(g1,0x112);
    DPPMAX(g0,0x114); DPPMAX(g1,0x114);
    DPPMAX(g0,0x118); DPPMAX(g1,0x118);
    DPPMAX(g0,0x142); DPPMAX(g1,0x142);
    DPPMAX(g0,0x143); DPPMAX(g1,0x143);
    float gm0 = __int_as_float(__builtin_amdgcn_readlane(__float_as_int(g0), 63));
    float gm1 = __int_as_float(__builtin_amdgcn_readlane(__float_as_int(g1), 63));

    unsigned long long m0 = __ballot(lmax[0] == gm0);
    unsigned long long m1 = __ballot(lmax[1] == gm1);
    int o0 = __ffsll(m0) - 1;
    int o1 = __ffsll(m1) - 1;
    if (lane == o0){
      int e0 = 15;
#pragma unroll
      for (int e = 14; e >= 0; e--) if (vv[0][e] == gm0) e0 = e;
      out0[it] = lane*16 + e0;
#pragma unroll
      for (int e = 0; e < 16; e++) if (e == e0) vv[0][e] = -1e30f;
      float nm = vv[0][0];
#pragma unroll
      for (int e = 1; e < 16; e++) nm = fmaxf(nm, vv[0][e]);
      lmax[0] = nm;
    }
    if (lane == o1){
      int e0 = 15;
#pragma unroll
      for (int e = 14; e >= 0; e--) if (vv[1][e] == gm1) e0 = e;
      out1[it] = lane*16 + e0;
#pragma unroll
      for (int e = 0; e < 16; e++) if (e == e0) vv[1][e] = -1e30f;
      float nm = vv[1][0];
#pragma unroll
      for (int e = 1; e < 16; e++) nm = fmaxf(nm, vv[1][e]);
      lmax[1] = nm;
    }
  }
}

// ---------------- L1 U|V: Z[n][0..63]=xt_n*wlT1, Z[n][64..127]=xt_n*dT1 (fp32, K=4) --------
__global__ __launch_bounds__(256) void k_uv1(const float* __restrict__ xt,
                                             const float* __restrict__ wlT, const float* __restrict__ dT,
                                             float* __restrict__ Z){
  int t = blockIdx.x*256 + threadIdx.x;          // 16384*32
  int n = t >> 5, q = t & 31;
  float4 xv = ld4(xt + (size_t)n*4);
  const float* wp = (q < 16) ? (wlT + q*4) : (dT + (q-16)*4);
  float4 a = make_float4(0.f,0.f,0.f,0.f);
  fma4(a, xv.x, ld4(wp + 0*64));
  fma4(a, xv.y, ld4(wp + 1*64));
  fma4(a, xv.z, ld4(wp + 2*64));
  fma4(a, xv.w, ld4(wp + 3*64));
  *(float4*)(Z + (size_t)n*128 + q*4) = a;
}

// ---------------- U|V dense GEMM (bf16 MFMA): Z[16384][2*Cout] = hb_in * [Wl;D]^T ----------
template<int K>
__global__ __launch_bounds__(256) void k_uv(const unsigned short* __restrict__ hbi,
                                            const unsigned short* __restrict__ wB,
                                            float* __restrict__ Z, int ldz){
  __shared__ char sm[20480];
  char* As = sm; char* Bs = sm + 10240;
  const int tid = threadIdx.x, lane = tid & 63, w = tid >> 6;
  const int l15 = lane & 15, quad = lane >> 4;
  const int n0 = blockIdx.x*128, r0 = blockIdx.y*128;

  f32x4 acc[2][8];
  f32x4 zero = {0.f,0.f,0.f,0.f};
#pragma unroll
  for (int i = 0; i < 2; i++)
#pragma unroll
    for (int j = 0; j < 8; j++) acc[i][j] = zero;

  for (int k0 = 0; k0 < K; k0 += 32){
#pragma unroll
    for (int i = 0; i < 2; i++){
      int e = tid + i*256;
      int r = e >> 2, sg = e & 3;
      *(float4*)(As + r*80 + sg*16) = *(const float4*)(hbi + ((size_t)(r0+r))*512 + k0 + sg*8);
      *(float4*)(Bs + r*80 + sg*16) = *(const float4*)(wB  + ((size_t)(n0+r))*K   + k0 + sg*8);
    }
    __syncthreads();
    short8 af0 = *(short8*)(As + (w*32 + l15)*80 + quad*16);
    short8 af1 = *(short8*)(As + (w*32 + 16 + l15)*80 + quad*16);
#pragma unroll
    for (int ns = 0; ns < 8; ns++){
      short8 bf = *(short8*)(Bs + (ns*16 + l15)*80 + quad*16);
      acc[0][ns] = mfma16(af0, bf, acc[0][ns]);
      acc[1][ns] = mfma16(af1, bf, acc[1][ns]);
    }
    __syncthreads();
  }

#pragma unroll
  for (int ms = 0; ms < 2; ms++){
#pragma unroll
    for (int ns = 0; ns < 8; ns++){
      f32x4 a = acc[ms][ns];
      int row = r0 + w*32 + ms*16 + quad*4;
      int col = n0 + ns*16 + l15;
#pragma unroll
      for (int r = 0; r < 4; r++)
        Z[(size_t)(row+r)*ldz + col] = a[r];
    }
  }
}

// ---------------- gather-max: out[i][o]=lrelu(max_j U[idx[i,j]][o] + V[i][o] + b[o]) --------
template<int COUT, int P, bool WF32>
__global__ __launch_bounds__(256) void k_gmax(const float* __restrict__ Z,
                                              const float* __restrict__ bias,
                                              const int* __restrict__ knn_idx,
                                              float* __restrict__ hf,
                                              unsigned short* __restrict__ hbo){
  constexpr int QPP = COUT/4;
  __shared__ int idxS[P*KNN];
  const int tid = threadIdx.x;
  const int p0 = blockIdx.x * P;
  for (int t = tid; t < P*KNN; t += 256) idxS[t] = knn_idx[(size_t)p0*KNN + t];
  __syncthreads();

  const int p = tid / QPP, q = tid - p*QPP;
  const int base = p0 & ~1023;
  const int ldz = 2*COUT;
  const float* Zq = Z + q*4;

  float4 m = make_float4(-1e30f,-1e30f,-1e30f,-1e30f);
#pragma unroll
  for (int j = 0; j < KNN; j++){
    int mr = idxS[p*KNN + j];
    max4(m, ld4(Zq + (size_t)(base + mr)*ldz));
  }
  float4 ctr = ld4(Z + (size_t)(p0+p)*ldz + COUT + q*4);
  float4 bs  = ld4(bias + q*4);
  float4 y;
  y.x = m.x + ctr.x + bs.x; y.x = fmaxf(y.x, 0.2f*y.x);
  y.y = m.y + ctr.y + bs.y; y.y = fmaxf(y.y, 0.2f*y.y);
  y.z = m.z + ctr.z + bs.z; y.z = fmaxf(y.z, 0.2f*y.z);
  y.w = m.w + ctr.w + bs.w; y.w = fmaxf(y.w, 0.2f*y.w);

  size_t pi = (size_t)(p0 + p);
  if (WF32) *(float4*)(hf + pi*256 + q*4) = y;
  ushort4 hv; hv.x = f2bf(y.x); hv.y = f2bf(y.y); hv.z = f2bf(y.z); hv.w = f2bf(y.w);
  *(ushort4*)(hbo + pi*512 + q*4) = hv;
}

// ---------------- conv5 (bf16 MFMA, 128x128 tile, K=512) + bias + lrelu + partial pool --------
__global__ __launch_bounds__(256) void k_conv5m(const unsigned short* __restrict__ hb,
                                                const unsigned short* __restrict__ w5b,
                                                const float* __restrict__ b5,
                                                float* __restrict__ pmax, float* __restrict__ psum){
  __shared__ char sm[20480 + 4096];
  char* As = sm; char* Bs = sm + 10240;
  float* red = (float*)(sm + 20480);
  const int tid = threadIdx.x, lane = tid & 63, w = tid >> 6;
  const int l15 = lane & 15, quad = lane >> 4;
  const int n0 = blockIdx.x*128, r0 = blockIdx.y*128;

  f32x4 acc[2][8];
  f32x4 zero = {0.f,0.f,0.f,0.f};
#pragma unroll
  for (int i = 0; i < 2; i++)
#pragma unroll
    for (int j = 0; j < 8; j++) acc[i][j] = zero;

  for (int k0 = 0; k0 < 512; k0 += 32){
#pragma unroll
    for (int i = 0; i < 2; i++){
      int e = tid + i*256;
      int r = e >> 2, sg = e & 3;
      *(float4*)(As + r*80 + sg*16) = *(const float4*)(hb  + ((size_t)(r0+r))*512 + k0 + sg*8);
      *(float4*)(Bs + r*80 + sg*16) = *(const float4*)(w5b + ((size_t)(n0+r))*512 + k0 + sg*8);
    }
    __syncthreads();
    short8 af0 = *(short8*)(As + (w*32 + l15)*80 + quad*16);
    short8 af1 = *(short8*)(As + (w*32 + 16 + l15)*80 + quad*16);
#pragma unroll
    for (int ns = 0; ns < 8; ns++){
      short8 bf = *(short8*)(Bs + (ns*16 + l15)*80 + quad*16);
      acc[0][ns] = mfma16(af0, bf, acc[0][ns]);
      acc[1][ns] = mfma16(af1, bf, acc[1][ns]);
    }
    __syncthreads();
  }

#pragma unroll
  for (int ns = 0; ns < 8; ns++){
    float bv = b5[n0 + ns*16 + l15];
    float mx = -1e30f, sum = 0.f;
#pragma unroll
    for (int ms = 0; ms < 2; ms++){
      float* a = (float*)&acc[ms][ns];
#pragma unroll
      for (int r = 0; r < 4; r++){
        float v = a[r] + bv; v = fmaxf(v, 0.2f*v);
        mx = fmaxf(mx, v); sum += v;
      }
    }
    for (int s = 16; s < 64; s <<= 1){
      mx = fmaxf(mx, __shfl_xor(mx, s));
      sum += __shfl_xor(sum, s);
    }
    if (quad == 0){ red[(w*8 + ns)*16 + l15] = mx; red[512 + (w*8 + ns)*16 + l15] = sum; }
  }
  __syncthreads();
  if (tid < 128){
    int ns = tid >> 4, ci = tid & 15;
    float mx = -1e30f, sum = 0.f;
#pragma unroll
    for (int w2 = 0; w2 < 4; w2++){
      mx = fmaxf(mx, red[(w2*8 + ns)*16 + ci]);
      sum += red[512 + (w2*8 + ns)*16 + ci];
    }
    pmax[(size_t)blockIdx.y*1024 + n0 + tid] = mx;
    psum[(size_t)blockIdx.y*1024 + n0 + tid] = sum;
  }
}

// ---------------- final pool: max & mean over N (8 chunks/batch) ----------------
__global__ __launch_bounds__(256) void k_pool(const float* __restrict__ pmax, const float* __restrict__ psum,
                                              float* __restrict__ pool){
  int i = blockIdx.x*256 + threadIdx.x;
  if (i >= BB*1024) return;
  int b = i >> 10, o = i & 1023;
  float mx = -1e30f, sm = 0.f;
  for (int ch = 0; ch < 8; ch++){
    mx = fmaxf(mx, pmax[(size_t)(b*8+ch)*1024 + o]);
    sm += psum[(size_t)(b*8+ch)*1024 + o];
  }
  pool[(size_t)b*2048 + o] = mx;
  pool[(size_t)b*2048 + 1024 + o] = sm * (1.f/1024.f);
}

// ---------------- FC1: 2048->512 ----------------
__global__ __launch_bounds__(256) void k_fc1(const float* __restrict__ pool,
                                             const float* __restrict__ wl1, const float* __restrict__ bn6,
                                             float* __restrict__ h1){
  __shared__ float pS[2048];
  const int b = blockIdx.y, t = threadIdx.x;
  for (int e = t; e < 512; e += 256) ((float4*)pS)[e] = ((const float4*)(pool + (size_t)b*2048))[e];
  __syncthreads();
  const int ol = t >> 4, ch = t & 15;
  const int o = blockIdx.x*16 + ol;
  const float* wr = wl1 + (size_t)o*2048;
  float acc = 0.f;
#pragma unroll
  for (int j = 0; j < 32; j++){
    int c = ch*4 + j*64;
    float4 wv = ld4(wr + c);
    acc += pS[c]*wv.x + pS[c+1]*wv.y + pS[c+2]*wv.z + pS[c+3]*wv.w;
  }
#pragma unroll
  for (int s = 1; s < 16; s <<= 1) acc += __shfl_xor(acc, s);
  if (ch == 0){
    float s = bn6[o] * rsqrtf(bn6[3*512+o] + BNEPS);
    float y = (acc - bn6[2*512+o])*s + bn6[512+o];
    h1[(size_t)b*512 + o] = fmaxf(y, 0.2f*y);
  }
}

// ---------------- FC2: 512->256 ----------------
__global__ __launch_bounds__(256) void k_fc2(const float* __restrict__ h1,
                                             const float* __restrict__ wl2, const float* __restrict__ bn7,
                                             float* __restrict__ h2){
  __shared__ float hS[512];
  const int b = blockIdx.y, t = threadIdx.x;
  if (t < 128) ((float4*)hS)[t] = ((const float4*)(h1 + (size_t)b*512))[t];
  __syncthreads();
  const int ol = t >> 4, ch = t & 15;
  const int o = blockIdx.x*16 + ol;
  const float* wr = wl2 + (size_t)o*512;
  float acc = 0.f;
#pragma unroll
  for (int j = 0; j < 8; j++){
    int c = ch*4 + j*64;
    float4 wv = ld4(wr + c);
    acc += hS[c]*wv.x + hS[c+1]*wv.y + hS[c+2]*wv.z + hS[c+3]*wv.w;
  }
#pragma unroll
  for (int s = 1; s < 16; s <<= 1) acc += __shfl_xor(acc, s);
  if (ch == 0){
    float s = bn7[o] * rsqrtf(bn7[3*256+o] + BNEPS);
    float y = (acc - bn7[2*256+o])*s + bn7[256+o];
    h2[(size_t)b*256 + o] = fmaxf(y, 0.2f*y);
  }
}

// ---------------- FC3: 256->40 ----------------
__global__ __launch_bounds__(64) void k_fc3(const float* __restrict__ h2,
                                            const float* __restrict__ wl3, const float* __restrict__ bl3,
                                            float* __restrict__ out){
  const int o = blockIdx.x, b = blockIdx.y, lane = threadIdx.x;
  float4 wv = ld4(wl3 + (size_t)o*256 + lane*4);
  float4 hv = ld4(h2 + (size_t)b*256 + lane*4);
  float acc = hv.x*wv.x + hv.y*wv.y + hv.z*wv.z + hv.w*wv.w;
#pragma unroll
  for (int s = 1; s < 64; s <<= 1) acc += __shfl_xor(acc, s);
  if (lane == 0) out[(size_t)b*40 + o] = acc + bl3[o];
}

extern "C" void kernel_launch(void* const* d_in, const int* in_sizes, int n_in,
                              void* d_out, int out_size, void* d_ws, size_t ws_size,
                              hipStream_t stream) {
  (void)in_sizes; (void)n_in; (void)out_size; (void)ws_size;
  const float* x   = (const float*)d_in[0];
  const float* w1  = (const float*)d_in[1];
  const float* bn1 = (const float*)d_in[2];
  const float* w2  = (const float*)d_in[3];
  const float* bn2 = (const float*)d_in[4];
  const float* w3  = (const float*)d_in[5];
  const float* bn3 = (const float*)d_in[6];
  const float* w4  = (const float*)d_in[7];
  const float* bn4 = (const float*)d_in[8];
  const float* w5  = (const float*)d_in[9];
  const float* bn5 = (const float*)d_in[10];
  const float* wl1 = (const float*)d_in[11];
  const float* bn6 = (const float*)d_in[12];
  const float* wl2 = (const float*)d_in[13];
  const float* bn7 = (const float*)d_in[14];
  const float* wl3 = (const float*)d_in[15];
  const float* bl3 = (const float*)d_in[16];
  float* out = (float*)d_out;

  float* ws    = (float*)d_ws;
  float* xt    = ws;                          // 65536
  float* sqb   = xt + 65536;                  // 16384
  int*   idxb  = (int*)(sqb + 16384);         // 327680 ints
  float* pd    = (float*)(idxb + 327680);     // 16777216 (Z aliases, used after topk)
  float* h     = pd + 16777216;               // 4194304 (fp32 acts, stride 256)
  float* wlT1  = h + 4194304;                 // 256
  float* dT1   = wlT1 + 256;                  // 256
  float* bias1 = dT1 + 256;                   // 64
  float* bias2 = bias1 + 64;                  // 64
  float* bias3 = bias2 + 64;                  // 128
  float* bias4 = bias3 + 128;                 // 256
  float* b5    = bias4 + 256;                 // 1024
  float* pmax  = b5 + 1024;                   // 131072
  float* psum  = pmax + 131072;               // 131072
  float* pool  = psum + 131072;               // 32768
  float* h1b   = pool + 32768;                // 8192
  float* h2b   = h1b + 8192;                  // 4096
  unsigned short* hb   = (unsigned short*)(h2b + 4096);    // 16384*512 bf16
  unsigned short* wlB2 = hb + (size_t)16384*512;            // 4096 (dB2 contiguous after)
  unsigned short* dB2  = wlB2 + 4096;
  unsigned short* wlB3 = dB2 + 4096;                        // 8192 (dB3 contiguous)
  unsigned short* dB3  = wlB3 + 8192;
  unsigned short* wlB4 = dB3 + 8192;                        // 32768 (dB4 contiguous)
  unsigned short* dB4  = wlB4 + 32768;
  unsigned short* w5b  = dB4 + 32768;                       // 524288
  float* Z = pd;

  k_transpose<<<64, 256, 0, stream>>>(x, xt);
  k_prep_w  <<<1,    256, 0, stream>>>(w1, bn1, wlT1, dT1, bias1, 3, 4, 64);
  k_prep_wbf<<<16,   256, 0, stream>>>(w2, bn2, wlB2, dB2, bias2, 64, 64);
  k_prep_wbf<<<32,   256, 0, stream>>>(w3, bn3, wlB3, dB3, bias3, 64, 128);
  k_prep_wbf<<<128,  256, 0, stream>>>(w4, bn4, wlB4, dB4, bias4, 128, 256);
  k_prep_w5b<<<2048, 256, 0, stream>>>(w5, bn5, w5b, b5);

  // ---- L1 (Cin=4 -> Cout=64) ----
  k_sq<<<64, 256, 0, stream>>>(xt, 4, 4, sqb);
  k_pd<<<dim3(8,8,16), 256, (size_t)2*128*8*4, stream>>>(xt, 4, 4, 4, 0, sqb, pd);
  k_topk<<<2048, 256, 0, stream>>>(pd, idxb);
  k_uv1<<<2048, 256, 0, stream>>>(xt, wlT1, dT1, Z);
  k_gmax<64,16,true><<<1024, 256, 0, stream>>>(Z, bias1, idxb, h, hb);

  // ---- L2 (64 -> 64) ----
  k_sq<<<64, 256, 0, stream>>>(h, 256, 64, sqb);
  k_pd<<<dim3(8,8,16), 256, (size_t)2*128*36*4, stream>>>(h, 256, 64, 32, 3, sqb, pd);
  k_topk<<<2048, 256, 0, stream>>>(pd, idxb);
  k_uv<64><<<dim3(1,128), 256, 0, stream>>>(hb, wlB2, Z, 128);
  k_gmax<64,16,true><<<1024, 256, 0, stream>>>(Z, bias2, idxb, h + 64, hb + 64);

  // ---- L3 (64 -> 128) ----
  k_sq<<<64, 256, 0, stream>>>(h + 64, 256, 64, sqb);
  k_pd<<<dim3(8,8,16), 256, (size_t)2*128*36*4, stream>>>(h + 64, 256, 64, 32, 3, sqb, pd);
  k_topk<<<2048, 256, 0, stream>>>(pd, idxb);
  k_uv<64><<<dim3(2,128), 256, 0, stream>>>(hb + 64, wlB3, Z, 256);
  k_gmax<128,8,true><<<2048, 256, 0, stream>>>(Z, bias3, idxb, h + 128, hb + 128);

  // ---- L4 (128 -> 256; bf16 out only) ----
  k_sq<<<64, 256, 0, stream>>>(h + 128, 256, 128, sqb);
  k_pd<<<dim3(8,8,16), 256, (size_t)2*128*36*4, stream>>>(h + 128, 256, 128, 32, 3, sqb, pd);
  k_topk<<<2048, 256, 0, stream>>>(pd, idxb);
  k_uv<128><<<dim3(4,128), 256, 0, stream>>>(hb + 128, wlB4, Z, 512);
  k_gmax<256,4,false><<<4096, 256, 0, stream>>>(Z, bias4, idxb, nullptr, hb + 256);

  // ---- conv5 + pool + FC head ----
  k_conv5m<<<dim3(8,128), 256, 0, stream>>>(hb, w5b, b5, pmax, psum);
  k_pool<<<64, 256, 0, stream>>>(pmax, psum, pool);
  k_fc1<<<dim3(32,16), 256, 0, stream>>>(pool, wl1, bn6, h1b);
  k_fc2<<<dim3(16,16), 256, 0, stream>>>(h1b, wl2, bn7, h2b);
  k_fc3<<<dim3(40,16), 64, 0, stream>>>(h2b, wl3, bl3, out);
}

// Round 13
// 578.152 us; speedup vs baseline: 1.0519x; 1.0519x over previous
//
#include <hip/hip_runtime.h>

#define BB 16
#define NN 1024
#define KNN 20
#define BNEPS 1e-5f

typedef __attribute__((ext_vector_type(8))) short short8;
typedef __attribute__((ext_vector_type(4))) float f32x4;

__device__ __forceinline__ float4 ld4(const float* p){ return *(const float4*)p; }
__device__ __forceinline__ void fma4(float4& a, float s, float4 w){
  a.x = fmaf(s, w.x, a.x); a.y = fmaf(s, w.y, a.y);
  a.z = fmaf(s, w.z, a.z); a.w = fmaf(s, w.w, a.w);
}
__device__ __forceinline__ void max4(float4& a, float4 v){
  a.x = fmaxf(a.x, v.x); a.y = fmaxf(a.y, v.y);
  a.z = fmaxf(a.z, v.z); a.w = fmaxf(a.w, v.w);
}
__device__ __forceinline__ unsigned short f2bf(float f){
  unsigned int u = __float_as_uint(f);
  u = (u + 0x7FFF + ((u >> 16) & 1)) >> 16;   // RNE, finite inputs
  return (unsigned short)u;
}
__device__ __forceinline__ f32x4 mfma16(short8 a, short8 b, f32x4 c){
  return __builtin_amdgcn_mfma_f32_16x16x32_bf16(a, b, c, 0, 0, 0);
}

// ---------------- transpose x (B,3,N) -> xt (B,N,4) padded ----------------
__global__ __launch_bounds__(256) void k_transpose(const float* __restrict__ x, float* __restrict__ xt){
  int i = blockIdx.x*256 + threadIdx.x;
  if (i >= BB*NN) return;
  int b = i >> 10, n = i & 1023;
  const float* xb = x + (size_t)b*3*NN;
  float4 v;
  v.x = xb[0*NN+n]; v.y = xb[1*NN+n]; v.z = xb[2*NN+n]; v.w = 0.f;
  ((float4*)xt)[i] = v;
}

// ---- L1 prep (fp32 [c][o] layout): BN folded ----
__global__ __launch_bounds__(256) void k_prep_w(const float* __restrict__ w, const float* __restrict__ bnp,
                                                float* __restrict__ wlT, float* __restrict__ dT,
                                                float* __restrict__ bias, int Cin, int Cpad, int Cout){
  int i = blockIdx.x*256 + threadIdx.x;
  if (i >= Cpad*Cout) return;
  int c = i / Cout, o = i - c*Cout;
  float s = bnp[o] * rsqrtf(bnp[3*Cout+o] + BNEPS);
  float wl = (c < Cin) ? w[(size_t)o*2*Cin + c] : 0.f;
  float wr = (c < Cin) ? w[(size_t)o*2*Cin + Cin + c] : 0.f;
  wlT[i] = wl * s;
  dT[i]  = (wr - wl) * s;
  if (c == 0) bias[o] = bnp[Cout+o] - bnp[2*Cout+o]*s;
}

// ---- bf16 prep: wlB[o][c], dB[o][c] (row-major over c), BN folded ----
__global__ __launch_bounds__(256) void k_prep_wbf(const float* __restrict__ w, const float* __restrict__ bnp,
                                                  unsigned short* __restrict__ wlB, unsigned short* __restrict__ dB,
                                                  float* __restrict__ bias, int Cin, int Cout){
  int i = blockIdx.x*256 + threadIdx.x;
  if (i >= Cin*Cout) return;
  int o = i / Cin, c = i - o*Cin;
  float s = bnp[o] * rsqrtf(bnp[3*Cout+o] + BNEPS);
  float wl = w[(size_t)o*2*Cin + c] * s;
  float wr = w[(size_t)o*2*Cin + Cin + c] * s;
  wlB[i] = f2bf(wl);
  dB[i]  = f2bf(wr - wl);
  if (c == 0) bias[o] = bnp[Cout+o] - bnp[2*Cout+o]*s;
}

__global__ __launch_bounds__(256) void k_prep_w5b(const float* __restrict__ w5, const float* __restrict__ bn5,
                                                  unsigned short* __restrict__ w5b, float* __restrict__ b5){
  int i = blockIdx.x*256 + threadIdx.x;
  if (i >= 1024*512) return;
  int o = i >> 9, c = i & 511;
  float s = bn5[o] * rsqrtf(bn5[3*1024+o] + BNEPS);
  w5b[i] = f2bf(w5[(size_t)o*512 + c] * s);
  if (c == 0) b5[o] = bn5[1024+o] - bn5[2*1024+o]*s;
}

// ---------------- sq[b*N+n] = sum_c in[n][c]^2 ----------------
__global__ __launch_bounds__(256) void k_sq(const float* __restrict__ xin, int rs, int Cin, float* __restrict__ sq){
  int i = blockIdx.x*256 + threadIdx.x;
  if (i >= BB*NN) return;
  const float* r = xin + (size_t)i*rs;
  float s = 0.f;
  for (int c = 0; c < Cin; c += 4){
    float4 v = ld4(r + c);
    s += v.x*v.x + v.y*v.y + v.z*v.z + v.w*v.w;
  }
  sq[i] = s;
}

// -------- pd symmetric: upper-triangle tiles only (36/batch vs 64) --------
// pd[n][m] = 2*dot(x_n,x_m) - sq[m]  (row-constant -sq[n] dropped: argmax-invariant)
// off-diagonal tiles also write transposed tile via LDS staging (bit-identical values:
// fmaf(a,b,c)==fmaf(b,a,c), same c-order). R10 inner loop untouched (VGPR~76 proven).
__global__ __launch_bounds__(256) void k_pd(const float* __restrict__ xin, int rs, int Cin, int CT, int lnf4,
                                            const float* __restrict__ sq, float* __restrict__ pd){
  extern __shared__ float lds[];
  const int pitch = CT + 4;
  float* As = lds;
  float* Bs = lds + 128*pitch;
  const int b = blockIdx.y;
  // decode upper-triangle tile index t -> (ti, tj), ti <= tj
  int t = blockIdx.x, ti = 0;
  while (t >= 8 - ti){ t -= (8 - ti); ti++; }
  const int tj = ti + t;
  const int n0 = ti*128, m0 = tj*128;
  const int tid = threadIdx.x;
  const int tx = tid & 15, ty = tid >> 4;
  const float* xb = xin + (size_t)b*NN*rs;
  float acc[8][8];
#pragma unroll
  for (int i = 0; i < 8; i++)
#pragma unroll
    for (int j = 0; j < 8; j++) acc[i][j] = 0.f;

  const int nf4 = CT >> 2;
  for (int c0 = 0; c0 < Cin; c0 += CT){
    for (int e = tid; e < 128*nf4; e += 256){
      int r = e >> lnf4, cc = (e & (nf4-1))*4;
      *(float4*)(As + r*pitch + cc) = ld4(xb + (size_t)(n0+r)*rs + c0 + cc);
      *(float4*)(Bs + r*pitch + cc) = ld4(xb + (size_t)(m0+r)*rs + c0 + cc);
    }
    __syncthreads();
    for (int c = 0; c < CT; c += 4){
      float4 a[8], bv[8];
#pragma unroll
      for (int i = 0; i < 8; i++) a[i]  = ld4(As + (ty+16*i)*pitch + c);
#pragma unroll
      for (int j = 0; j < 8; j++) bv[j] = ld4(Bs + (tx+16*j)*pitch + c);
#pragma unroll
      for (int i = 0; i < 8; i++)
#pragma unroll
        for (int j = 0; j < 8; j++){
          acc[i][j] = fmaf(a[i].x, bv[j].x, acc[i][j]);
          acc[i][j] = fmaf(a[i].y, bv[j].y, acc[i][j]);
          acc[i][j] = fmaf(a[i].z, bv[j].z, acc[i][j]);
          acc[i][j] = fmaf(a[i].w, bv[j].w, acc[i][j]);
        }
    }
    __syncthreads();
  }

  // direct write: pd[n][m] = 2*acc - sq[m]  (coalesced)
#pragma unroll
  for (int i = 0; i < 8; i++){
    int n = n0 + ty + 16*i;
#pragma unroll
    for (int j = 0; j < 8; j++){
      int m = m0 + tx + 16*j;
      pd[((size_t)b*NN + n)*NN + m] = 2.f*acc[i][j] - sq[b*NN + m];
    }
  }

  // transposed write for off-diagonal tiles: pd[m][n] = 2*acc - sq[n]
  if (ti != tj){
    const int PT = 132;                       // 64 x 132 floats = 33.8 KB (fits in staging LDS)
    float* Ltr = lds;
    float sqn[8];
#pragma unroll
    for (int i = 0; i < 8; i++) sqn[i] = sq[b*NN + n0 + ty + 16*i];
#pragma unroll
    for (int h = 0; h < 2; h++){
      __syncthreads();                        // staging (or previous half) fully consumed
#pragma unroll
      for (int i = 0; i < 8; i++)
#pragma unroll
        for (int j = 4*h; j < 4*h+4; j++)
          Ltr[(tx + 16*j - 64*h)*PT + ty + 16*i] = 2.f*acc[i][j] - sqn[i];
      __syncthreads();
      for (int e = tid; e < 64*32; e += 256){
        int r = e >> 5, c4 = (e & 31)*4;
        *(float4*)(pd + ((size_t)b*NN + m0 + 64*h + r)*NN + n0 + c4) = *(float4*)(Ltr + r*PT + c4);
      }
    }
  }
}

// ------------ top-k v3 (k=20): 2 rows/wave (interleaved shfl chains), ballot owner ------------
// tie semantics match jax.lax.top_k: value desc, index asc
__global__ __launch_bounds__(256) void k_topk(const float* __restrict__ pd, int* __restrict__ idxOut){
  int w = threadIdx.x >> 6, lane = threadIdx.x & 63;
  int bn0 = (blockIdx.x*4 + w)*2;
  float vv[2][16];
  float lmax[2];
#pragma unroll
  for (int rr = 0; rr < 2; rr++){
    const float* row = pd + (size_t)(bn0+rr)*NN;
#pragma unroll
    for (int r = 0; r < 4; r++){
      float4 t = ld4(row + lane*16 + r*4);
      vv[rr][r*4+0] = t.x; vv[rr][r*4+1] = t.y; vv[rr][r*4+2] = t.z; vv[rr][r*4+3] = t.w;
    }
    float m = vv[rr][0];
#pragma unroll
    for (int e = 1; e < 16; e++) m = fmaxf(m, vv[rr][e]);
    lmax[rr] = m;
  }

  int* out0 = idxOut + (size_t)bn0*KNN;
  int* out1 = out0 + KNN;
  for (int it = 0; it < KNN; it++){
    float g0 = lmax[0], g1 = lmax[1];
#pragma unroll
    for (int s = 1; s < 64; s <<= 1){
      g0 = fmaxf(g0, __shfl_xor(g0, s));
      g1 = fmaxf(g1, __shfl_xor(g1, s));
    }
    unsigned long long m0 = __ballot(lmax[0] == g0);
    unsigned long long m1 = __ballot(lmax[1] == g1);
    int o0 = __ffsll(m0) - 1;
    int o1 = __ffsll(m1) - 1;
    if (lane == o0){
      int e0 = 15;
#pragma unroll
      for (int e = 14; e >= 0; e--) if (vv[0][e] == g0) e0 = e;
      out0[it] = lane*16 + e0;
#pragma unroll
      for (int e = 0; e < 16; e++) if (e == e0) vv[0][e] = -1e30f;
      float nm = vv[0][0];
#pragma unroll
      for (int e = 1; e < 16; e++) nm = fmaxf(nm, vv[0][e]);
      lmax[0] = nm;
    }
    if (lane == o1){
      int e0 = 15;
#pragma unroll
      for (int e = 14; e >= 0; e--) if (vv[1][e] == g1) e0 = e;
      out1[it] = lane*16 + e0;
#pragma unroll
      for (int e = 0; e < 16; e++) if (e == e0) vv[1][e] = -1e30f;
      float nm = vv[1][0];
#pragma unroll
      for (int e = 1; e < 16; e++) nm = fmaxf(nm, vv[1][e]);
      lmax[1] = nm;
    }
  }
}

// ---------------- L1 U|V: Z[n][0..63]=xt_n*wlT1, Z[n][64..127]=xt_n*dT1 (fp32, K=4) --------
__global__ __launch_bounds__(256) void k_uv1(const float* __restrict__ xt,
                                             const float* __restrict__ wlT, const float* __restrict__ dT,
                                             float* __restrict__ Z){
  int t = blockIdx.x*256 + threadIdx.x;          // 16384*32
  int n = t >> 5, q = t & 31;
  float4 xv = ld4(xt + (size_t)n*4);
  const float* wp = (q < 16) ? (wlT + q*4) : (dT + (q-16)*4);
  float4 a = make_float4(0.f,0.f,0.f,0.f);
  fma4(a, xv.x, ld4(wp + 0*64));
  fma4(a, xv.y, ld4(wp + 1*64));
  fma4(a, xv.z, ld4(wp + 2*64));
  fma4(a, xv.w, ld4(wp + 3*64));
  *(float4*)(Z + (size_t)n*128 + q*4) = a;
}

// ---------------- U|V dense GEMM (bf16 MFMA): Z[16384][2*Cout] = hb_in * [Wl;D]^T ----------
template<int K>
__global__ __launch_bounds__(256) void k_uv(const unsigned short* __restrict__ hbi,
                                            const unsigned short* __restrict__ wB,
                                            float* __restrict__ Z, int ldz){
  __shared__ char sm[20480];
  char* As = sm; char* Bs = sm + 10240;
  const int tid = threadIdx.x, lane = tid & 63, w = tid >> 6;
  const int l15 = lane & 15, quad = lane >> 4;
  const int n0 = blockIdx.x*128, r0 = blockIdx.y*128;

  f32x4 acc[2][8];
  f32x4 zero = {0.f,0.f,0.f,0.f};
#pragma unroll
  for (int i = 0; i < 2; i++)
#pragma unroll
    for (int j = 0; j < 8; j++) acc[i][j] = zero;

  for (int k0 = 0; k0 < K; k0 += 32){
#pragma unroll
    for (int i = 0; i < 2; i++){
      int e = tid + i*256;
      int r = e >> 2, sg = e & 3;
      *(float4*)(As + r*80 + sg*16) = *(const float4*)(hbi + ((size_t)(r0+r))*512 + k0 + sg*8);
      *(float4*)(Bs + r*80 + sg*16) = *(const float4*)(wB  + ((size_t)(n0+r))*K   + k0 + sg*8);
    }
    __syncthreads();
    short8 af0 = *(short8*)(As + (w*32 + l15)*80 + quad*16);
    short8 af1 = *(short8*)(As + (w*32 + 16 + l15)*80 + quad*16);
#pragma unroll
    for (int ns = 0; ns < 8; ns++){
      short8 bf = *(short8*)(Bs + (ns*16 + l15)*80 + quad*16);
      acc[0][ns] = mfma16(af0, bf, acc[0][ns]);
      acc[1][ns] = mfma16(af1, bf, acc[1][ns]);
    }
    __syncthreads();
  }

#pragma unroll
  for (int ms = 0; ms < 2; ms++){
#pragma unroll
    for (int ns = 0; ns < 8; ns++){
      f32x4 a = acc[ms][ns];
      int row = r0 + w*32 + ms*16 + quad*4;
      int col = n0 + ns*16 + l15;
#pragma unroll
      for (int r = 0; r < 4; r++)
        Z[(size_t)(row+r)*ldz + col] = a[r];
    }
  }
}

// ---------------- gather-max: out[i][o]=lrelu(max_j U[idx[i,j]][o] + V[i][o] + b[o]) --------
template<int COUT, int P, bool WF32>
__global__ __launch_bounds__(256) void k_gmax(const float* __restrict__ Z,
                                              const float* __restrict__ bias,
                                              const int* __restrict__ knn_idx,
                                              float* __restrict__ hf,
                                              unsigned short* __restrict__ hbo){
  constexpr int QPP = COUT/4;
  __shared__ int idxS[P*KNN];
  const int tid = threadIdx.x;
  const int p0 = blockIdx.x * P;
  for (int t = tid; t < P*KNN; t += 256) idxS[t] = knn_idx[(size_t)p0*KNN + t];
  __syncthreads();

  const int p = tid / QPP, q = tid - p*QPP;
  const int base = p0 & ~1023;
  const int ldz = 2*COUT;
  const float* Zq = Z + q*4;

  float4 m = make_float4(-1e30f,-1e30f,-1e30f,-1e30f);
#pragma unroll
  for (int j = 0; j < KNN; j++){
    int mr = idxS[p*KNN + j];
    max4(m, ld4(Zq + (size_t)(base + mr)*ldz));
  }
  float4 ctr = ld4(Z + (size_t)(p0+p)*ldz + COUT + q*4);
  float4 bs  = ld4(bias + q*4);
  float4 y;
  y.x = m.x + ctr.x + bs.x; y.x = fmaxf(y.x, 0.2f*y.x);
  y.y = m.y + ctr.y + bs.y; y.y = fmaxf(y.y, 0.2f*y.y);
  y.z = m.z + ctr.z + bs.z; y.z = fmaxf(y.z, 0.2f*y.z);
  y.w = m.w + ctr.w + bs.w; y.w = fmaxf(y.w, 0.2f*y.w);

  size_t pi = (size_t)(p0 + p);
  if (WF32) *(float4*)(hf + pi*256 + q*4) = y;
  ushort4 hv; hv.x = f2bf(y.x); hv.y = f2bf(y.y); hv.z = f2bf(y.z); hv.w = f2bf(y.w);
  *(ushort4*)(hbo + pi*512 + q*4) = hv;
}

// ---------------- conv5 (bf16 MFMA, 128x128 tile, K=512) + bias + lrelu + partial pool --------
__global__ __launch_bounds__(256) void k_conv5m(const unsigned short* __restrict__ hb,
                                                const unsigned short* __restrict__ w5b,
                                                const float* __restrict__ b5,
                                                float* __restrict__ pmax, float* __restrict__ psum){
  __shared__ char sm[20480 + 4096];
  char* As = sm; char* Bs = sm + 10240;
  float* red = (float*)(sm + 20480);
  const int tid = threadIdx.x, lane = tid & 63, w = tid >> 6;
  const int l15 = lane & 15, quad = lane >> 4;
  const int n0 = blockIdx.x*128, r0 = blockIdx.y*128;

  f32x4 acc[2][8];
  f32x4 zero = {0.f,0.f,0.f,0.f};
#pragma unroll
  for (int i = 0; i < 2; i++)
#pragma unroll
    for (int j = 0; j < 8; j++) acc[i][j] = zero;

  for (int k0 = 0; k0 < 512; k0 += 32){
#pragma unroll
    for (int i = 0; i < 2; i++){
      int e = tid + i*256;
      int r = e >> 2, sg = e & 3;
      *(float4*)(As + r*80 + sg*16) = *(const float4*)(hb  + ((size_t)(r0+r))*512 + k0 + sg*8);
      *(float4*)(Bs + r*80 + sg*16) = *(const float4*)(w5b + ((size_t)(n0+r))*512 + k0 + sg*8);
    }
    __syncthreads();
    short8 af0 = *(short8*)(As + (w*32 + l15)*80 + quad*16);
    short8 af1 = *(short8*)(As + (w*32 + 16 + l15)*80 + quad*16);
#pragma unroll
    for (int ns = 0; ns < 8; ns++){
      short8 bf = *(short8*)(Bs + (ns*16 + l15)*80 + quad*16);
      acc[0][ns] = mfma16(af0, bf, acc[0][ns]);
      acc[1][ns] = mfma16(af1, bf, acc[1][ns]);
    }
    __syncthreads();
  }

#pragma unroll
  for (int ns = 0; ns < 8; ns++){
    float bv = b5[n0 + ns*16 + l15];
    float mx = -1e30f, sum = 0.f;
#pragma unroll
    for (int ms = 0; ms < 2; ms++){
      float* a = (float*)&acc[ms][ns];
#pragma unroll
      for (int r = 0; r < 4; r++){
        float v = a[r] + bv; v = fmaxf(v, 0.2f*v);
        mx = fmaxf(mx, v); sum += v;
      }
    }
    for (int s = 16; s < 64; s <<= 1){
      mx = fmaxf(mx, __shfl_xor(mx, s));
      sum += __shfl_xor(sum, s);
    }
    if (quad == 0){ red[(w*8 + ns)*16 + l15] = mx; red[512 + (w*8 + ns)*16 + l15] = sum; }
  }
  __syncthreads();
  if (tid < 128){
    int ns = tid >> 4, ci = tid & 15;
    float mx = -1e30f, sum = 0.f;
#pragma unroll
    for (int w2 = 0; w2 < 4; w2++){
      mx = fmaxf(mx, red[(w2*8 + ns)*16 + ci]);
      sum += red[512 + (w2*8 + ns)*16 + ci];
    }
    pmax[(size_t)blockIdx.y*1024 + n0 + tid] = mx;
    psum[(size_t)blockIdx.y*1024 + n0 + tid] = sum;
  }
}

// ---------------- final pool: max & mean over N (8 chunks/batch) ----------------
__global__ __launch_bounds__(256) void k_pool(const float* __restrict__ pmax, const float* __restrict__ psum,
                                              float* __restrict__ pool){
  int i = blockIdx.x*256 + threadIdx.x;
  if (i >= BB*1024) return;
  int b = i >> 10, o = i & 1023;
  float mx = -1e30f, sm = 0.f;
  for (int ch = 0; ch < 8; ch++){
    mx = fmaxf(mx, pmax[(size_t)(b*8+ch)*1024 + o]);
    sm += psum[(size_t)(b*8+ch)*1024 + o];
  }
  pool[(size_t)b*2048 + o] = mx;
  pool[(size_t)b*2048 + 1024 + o] = sm * (1.f/1024.f);
}

// ---------------- FC1: 2048->512 ----------------
__global__ __launch_bounds__(256) void k_fc1(const float* __restrict__ pool,
                                             const float* __restrict__ wl1, const float* __restrict__ bn6,
                                             float* __restrict__ h1){
  __shared__ float pS[2048];
  const int b = blockIdx.y, t = threadIdx.x;
  for (int e = t; e < 512; e += 256) ((float4*)pS)[e] = ((const float4*)(pool + (size_t)b*2048))[e];
  __syncthreads();
  const int ol = t >> 4, ch = t & 15;
  const int o = blockIdx.x*16 + ol;
  const float* wr = wl1 + (size_t)o*2048;
  float acc = 0.f;
#pragma unroll
  for (int j = 0; j < 32; j++){
    int c = ch*4 + j*64;
    float4 wv = ld4(wr + c);
    acc += pS[c]*wv.x + pS[c+1]*wv.y + pS[c+2]*wv.z + pS[c+3]*wv.w;
  }
#pragma unroll
  for (int s = 1; s < 16; s <<= 1) acc += __shfl_xor(acc, s);
  if (ch == 0){
    float s = bn6[o] * rsqrtf(bn6[3*512+o] + BNEPS);
    float y = (acc - bn6[2*512+o])*s + bn6[512+o];
    h1[(size_t)b*512 + o] = fmaxf(y, 0.2f*y);
  }
}

// ---------------- FC2: 512->256 ----------------
__global__ __launch_bounds__(256) void k_fc2(const float* __restrict__ h1,
                                             const float* __restrict__ wl2, const float* __restrict__ bn7,
                                             float* __restrict__ h2){
  __shared__ float hS[512];
  const int b = blockIdx.y, t = threadIdx.x;
  if (t < 128) ((float4*)hS)[t] = ((const float4*)(h1 + (size_t)b*512))[t];
  __syncthreads();
  const int ol = t >> 4, ch = t & 15;
  const int o = blockIdx.x*16 + ol;
  const float* wr = wl2 + (size_t)o*512;
  float acc = 0.f;
#pragma unroll
  for (int j = 0; j < 8; j++){
    int c = ch*4 + j*64;
    float4 wv = ld4(wr + c);
    acc += hS[c]*wv.x + hS[c+1]*wv.y + hS[c+2]*wv.z + hS[c+3]*wv.w;
  }
#pragma unroll
  for (int s = 1; s < 16; s <<= 1) acc += __shfl_xor(acc, s);
  if (ch == 0){
    float s = bn7[o] * rsqrtf(bn7[3*256+o] + BNEPS);
    float y = (acc - bn7[2*256+o])*s + bn7[256+o];
    h2[(size_t)b*256 + o] = fmaxf(y, 0.2f*y);
  }
}

// ---------------- FC3: 256->40 ----------------
__global__ __launch_bounds__(64) void k_fc3(const float* __restrict__ h2,
                                            const float* __restrict__ wl3, const float* __restrict__ bl3,
                                            float* __restrict__ out){
  const int o = blockIdx.x, b = blockIdx.y, lane = threadIdx.x;
  float4 wv = ld4(wl3 + (size_t)o*256 + lane*4);
  float4 hv = ld4(h2 + (size_t)b*256 + lane*4);
  float acc = hv.x*wv.x + hv.y*wv.y + hv.z*wv.z + hv.w*wv.w;
#pragma unroll
  for (int s = 1; s < 64; s <<= 1) acc += __shfl_xor(acc, s);
  if (lane == 0) out[(size_t)b*40 + o] = acc + bl3[o];
}

extern "C" void kernel_launch(void* const* d_in, const int* in_sizes, int n_in,
                              void* d_out, int out_size, void* d_ws, size_t ws_size,
                              hipStream_t stream) {
  (void)in_sizes; (void)n_in; (void)out_size; (void)ws_size;
  const float* x   = (const float*)d_in[0];
  const float* w1  = (const float*)d_in[1];
  const float* bn1 = (const float*)d_in[2];
  const float* w2  = (const float*)d_in[3];
  const float* bn2 = (const float*)d_in[4];
  const float* w3  = (const float*)d_in[5];
  const float* bn3 = (const float*)d_in[6];
  const float* w4  = (const float*)d_in[7];
  const float* bn4 = (const float*)d_in[8];
  const float* w5  = (const float*)d_in[9];
  const float* bn5 = (const float*)d_in[10];
  const float* wl1 = (const float*)d_in[11];
  const float* bn6 = (const float*)d_in[12];
  const float* wl2 = (const float*)d_in[13];
  const float* bn7 = (const float*)d_in[14];
  const float* wl3 = (const float*)d_in[15];
  const float* bl3 = (const float*)d_in[16];
  float* out = (float*)d_out;

  float* ws    = (float*)d_ws;
  float* xt    = ws;                          // 65536
  float* sqb   = xt + 65536;                  // 16384
  int*   idxb  = (int*)(sqb + 16384);         // 327680 ints
  float* pd    = (float*)(idxb + 327680);     // 16777216 (Z aliases, used after topk)
  float* h     = pd + 16777216;               // 4194304 (fp32 acts, stride 256)
  float* wlT1  = h + 4194304;                 // 256
  float* dT1   = wlT1 + 256;                  // 256
  float* bias1 = dT1 + 256;                   // 64
  float* bias2 = bias1 + 64;                  // 64
  float* bias3 = bias2 + 64;                  // 128
  float* bias4 = bias3 + 128;                 // 256
  float* b5    = bias4 + 256;                 // 1024
  float* pmax  = b5 + 1024;                   // 131072
  float* psum  = pmax + 131072;               // 131072
  float* pool  = psum + 131072;               // 32768
  float* h1b   = pool + 32768;                // 8192
  float* h2b   = h1b + 8192;                  // 4096
  unsigned short* hb   = (unsigned short*)(h2b + 4096);    // 16384*512 bf16
  unsigned short* wlB2 = hb + (size_t)16384*512;            // 4096 (dB2 contiguous after)
  unsigned short* dB2  = wlB2 + 4096;
  unsigned short* wlB3 = dB2 + 4096;                        // 8192 (dB3 contiguous)
  unsigned short* dB3  = wlB3 + 8192;
  unsigned short* wlB4 = dB3 + 8192;                        // 32768 (dB4 contiguous)
  unsigned short* dB4  = wlB4 + 32768;
  unsigned short* w5b  = dB4 + 32768;                       // 524288
  float* Z = pd;

  k_transpose<<<64, 256, 0, stream>>>(x, xt);
  k_prep_w  <<<1,    256, 0, stream>>>(w1, bn1, wlT1, dT1, bias1, 3, 4, 64);
  k_prep_wbf<<<16,   256, 0, stream>>>(w2, bn2, wlB2, dB2, bias2, 64, 64);
  k_prep_wbf<<<32,   256, 0, stream>>>(w3, bn3, wlB3, dB3, bias3, 64, 128);
  k_prep_wbf<<<128,  256, 0, stream>>>(w4, bn4, wlB4, dB4, bias4, 128, 256);
  k_prep_w5b<<<2048, 256, 0, stream>>>(w5, bn5, w5b, b5);

  // pd LDS: max(staging 2*128*(CT+4)*4, transpose 64*132*4 = 33792)
  const size_t PD_LDS32 = 36864;   // CT=32 staging dominates
  const size_t PD_LDS4  = 33792;   // CT=4: transpose buffer dominates

  // ---- L1 (Cin=4 -> Cout=64) ----
  k_sq<<<64, 256, 0, stream>>>(xt, 4, 4, sqb);
  k_pd<<<dim3(36,16), 256, PD_LDS4, stream>>>(xt, 4, 4, 4, 0, sqb, pd);
  k_topk<<<2048, 256, 0, stream>>>(pd, idxb);
  k_uv1<<<2048, 256, 0, stream>>>(xt, wlT1, dT1, Z);
  k_gmax<64,16,true><<<1024, 256, 0, stream>>>(Z, bias1, idxb, h, hb);

  // ---- L2 (64 -> 64) ----
  k_sq<<<64, 256, 0, stream>>>(h, 256, 64, sqb);
  k_pd<<<dim3(36,16), 256, PD_LDS32, stream>>>(h, 256, 64, 32, 3, sqb, pd);
  k_topk<<<2048, 256, 0, stream>>>(pd, idxb);
  k_uv<64><<<dim3(1,128), 256, 0, stream>>>(hb, wlB2, Z, 128);
  k_gmax<64,16,true><<<1024, 256, 0, stream>>>(Z, bias2, idxb, h + 64, hb + 64);

  // ---- L3 (64 -> 128) ----
  k_sq<<<64, 256, 0, stream>>>(h + 64, 256, 64, sqb);
  k_pd<<<dim3(36,16), 256, PD_LDS32, stream>>>(h + 64, 256, 64, 32, 3, sqb, pd);
  k_topk<<<2048, 256, 0, stream>>>(pd, idxb);
  k_uv<64><<<dim3(2,128), 256, 0, stream>>>(hb + 64, wlB3, Z, 256);
  k_gmax<128,8,true><<<2048, 256, 0, stream>>>(Z, bias3, idxb, h + 128, hb + 128);

  // ---- L4 (128 -> 256; bf16 out only) ----
  k_sq<<<64, 256, 0, stream>>>(h + 128, 256, 128, sqb);
  k_pd<<<dim3(36,16), 256, PD_LDS32, stream>>>(h + 128, 256, 128, 32, 3, sqb, pd);
  k_topk<<<2048, 256, 0, stream>>>(pd, idxb);
  k_uv<128><<<dim3(4,128), 256, 0, stream>>>(hb + 128, wlB4, Z, 512);
  k_gmax<256,4,false><<<4096, 256, 0, stream>>>(Z, bias4, idxb, nullptr, hb + 256);

  // ---- conv5 + pool + FC head ----
  k_conv5m<<<dim3(8,128), 256, 0, stream>>>(hb, w5b, b5, pmax, psum);
  k_pool<<<64, 256, 0, stream>>>(pmax, psum, pool);
  k_fc1<<<dim3(32,16), 256, 0, stream>>>(pool, wl1, bn6, h1b);
  k_fc2<<<dim3(16,16), 256, 0, stream>>>(h1b, wl2, bn7, h2b);
  k_fc3<<<dim3(40,16), 64, 0, stream>>>(h2b, wl3, bl3, out);
}

// Round 14
// 475.529 us; speedup vs baseline: 1.2789x; 1.2158x over previous
//
#include <hip/hip_runtime.h>

#define BB 16
#define NN 1024
#define KNN 20
#define BNEPS 1e-5f

typedef __attribute__((ext_vector_type(8))) short short8;
typedef __attribute__((ext_vector_type(4))) float f32x4;

__device__ __forceinline__ float4 ld4(const float* p){ return *(const float4*)p; }
__device__ __forceinline__ void fma4(float4& a, float s, float4 w){
  a.x = fmaf(s, w.x, a.x); a.y = fmaf(s, w.y, a.y);
  a.z = fmaf(s, w.z, a.z); a.w = fmaf(s, w.w, a.w);
}
__device__ __forceinline__ void max4(float4& a, float4 v){
  a.x = fmaxf(a.x, v.x); a.y = fmaxf(a.y, v.y);
  a.z = fmaxf(a.z, v.z); a.w = fmaxf(a.w, v.w);
}
__device__ __forceinline__ unsigned short f2bf(float f){
  unsigned int u = __float_as_uint(f);
  u = (u + 0x7FFF + ((u >> 16) & 1)) >> 16;   // RNE, finite inputs
  return (unsigned short)u;
}
__device__ __forceinline__ f32x4 mfma16(short8 a, short8 b, f32x4 c){
  return __builtin_amdgcn_mfma_f32_16x16x32_bf16(a, b, c, 0, 0, 0);
}

// build exact (value desc, index asc) top-3 of a lane's 16 row elements, excluding km bits
__device__ __forceinline__ void top3_build(const float* rp, int kmr,
                                           float& a0, float& a1, float& a2,
                                           int& i0, int& i1, int& i2){
  a0 = -1e30f; a1 = -1e30f; a2 = -1e30f; i0 = 0; i1 = 0; i2 = 0;
#pragma unroll
  for (int r = 0; r < 4; r++){
    float4 t = ld4(rp + r*4);
    float tv[4] = {t.x, t.y, t.z, t.w};
#pragma unroll
    for (int q = 0; q < 4; q++){
      int e = r*4 + q;
      float v = ((kmr >> e) & 1) ? -1e30f : tv[q];
      bool b0 = v > a0, b1 = v > a1, b2 = v > a2;
      a2 = b1 ? a1 : (b2 ? v : a2); i2 = b1 ? i1 : (b2 ? e : i2);
      a1 = b0 ? a0 : (b1 ? v : a1); i1 = b0 ? i0 : (b1 ? e : i1);
      a0 = b0 ? v  : a0;            i0 = b0 ? e : i0;
    }
  }
}

// ---------------- transpose x (B,3,N) -> xt (B,N,4) padded; also sq for L1 ----------------
__global__ __launch_bounds__(256) void k_transpose(const float* __restrict__ x, float* __restrict__ xt,
                                                   float* __restrict__ sq){
  int i = blockIdx.x*256 + threadIdx.x;
  if (i >= BB*NN) return;
  int b = i >> 10, n = i & 1023;
  const float* xb = x + (size_t)b*3*NN;
  float4 v;
  v.x = xb[0*NN+n]; v.y = xb[1*NN+n]; v.z = xb[2*NN+n]; v.w = 0.f;
  ((float4*)xt)[i] = v;
  sq[i] = v.x*v.x + v.y*v.y + v.z*v.z;
}

// ---- device preps ----
__device__ __forceinline__ void prep_w_dev(int i, const float* w, const float* bnp,
                                           float* wlT, float* dT, float* bias, int Cin, int Cpad, int Cout){
  if (i >= Cpad*Cout) return;
  int c = i / Cout, o = i - c*Cout;
  float s = bnp[o] * rsqrtf(bnp[3*Cout+o] + BNEPS);
  float wl = (c < Cin) ? w[(size_t)o*2*Cin + c] : 0.f;
  float wr = (c < Cin) ? w[(size_t)o*2*Cin + Cin + c] : 0.f;
  wlT[i] = wl * s;
  dT[i]  = (wr - wl) * s;
  if (c == 0) bias[o] = bnp[Cout+o] - bnp[2*Cout+o]*s;
}
__device__ __forceinline__ void prep_wbf_dev(int i, const float* w, const float* bnp,
                                             unsigned short* wlB, unsigned short* dB, float* bias,
                                             int Cin, int Cout){
  if (i >= Cin*Cout) return;
  int o = i / Cin, c = i - o*Cin;
  float s = bnp[o] * rsqrtf(bnp[3*Cout+o] + BNEPS);
  float wl = w[(size_t)o*2*Cin + c] * s;
  float wr = w[(size_t)o*2*Cin + Cin + c] * s;
  wlB[i] = f2bf(wl);
  dB[i]  = f2bf(wr - wl);
  if (c == 0) bias[o] = bnp[Cout+o] - bnp[2*Cout+o]*s;
}

// ---- single merged prep kernel: grid 2225 blocks ----
__global__ __launch_bounds__(256) void k_prep_all(const float* __restrict__ w1, const float* __restrict__ bn1,
                                                  const float* __restrict__ w2, const float* __restrict__ bn2,
                                                  const float* __restrict__ w3, const float* __restrict__ bn3,
                                                  const float* __restrict__ w4, const float* __restrict__ bn4,
                                                  const float* __restrict__ w5, const float* __restrict__ bn5,
                                                  float* __restrict__ wlT1, float* __restrict__ dT1, float* __restrict__ bias1,
                                                  unsigned short* __restrict__ wlB2, unsigned short* __restrict__ dB2, float* __restrict__ bias2,
                                                  unsigned short* __restrict__ wlB3, unsigned short* __restrict__ dB3, float* __restrict__ bias3,
                                                  unsigned short* __restrict__ wlB4, unsigned short* __restrict__ dB4, float* __restrict__ bias4,
                                                  unsigned short* __restrict__ w5b, float* __restrict__ b5){
  int bid = blockIdx.x, t = threadIdx.x;
  if (bid < 1){
    prep_w_dev(t, w1, bn1, wlT1, dT1, bias1, 3, 4, 64);
  } else if (bid < 17){
    prep_wbf_dev((bid-1)*256 + t, w2, bn2, wlB2, dB2, bias2, 64, 64);
  } else if (bid < 49){
    prep_wbf_dev((bid-17)*256 + t, w3, bn3, wlB3, dB3, bias3, 64, 128);
  } else if (bid < 177){
    prep_wbf_dev((bid-49)*256 + t, w4, bn4, wlB4, dB4, bias4, 128, 256);
  } else {
    int i = (bid-177)*256 + t;
    int o = i >> 9, c = i & 511;
    float s = bn5[o] * rsqrtf(bn5[3*1024+o] + BNEPS);
    w5b[i] = f2bf(w5[(size_t)o*512 + c] * s);
    if (c == 0) b5[o] = bn5[1024+o] - bn5[2*1024+o]*s;
  }
}

// ---------------- sq[b*N+n] = sum_c in[n][c]^2 (L2-L4) ----------------
__global__ __launch_bounds__(256) void k_sq(const float* __restrict__ xin, int rs, int Cin, float* __restrict__ sq){
  int i = blockIdx.x*256 + threadIdx.x;
  if (i >= BB*NN) return;
  const float* r = xin + (size_t)i*rs;
  float s = 0.f;
  for (int c = 0; c < Cin; c += 4){
    float4 v = ld4(r + c);
    s += v.x*v.x + v.y*v.y + v.z*v.z + v.w*v.w;
  }
  sq[i] = s;
}

// -------- pd symmetric: upper-triangle tiles only (36/batch) --------
__global__ __launch_bounds__(256) void k_pd(const float* __restrict__ xin, int rs, int Cin, int CT, int lnf4,
                                            const float* __restrict__ sq, float* __restrict__ pd){
  extern __shared__ float lds[];
  const int pitch = CT + 4;
  float* As = lds;
  float* Bs = lds + 128*pitch;
  const int b = blockIdx.y;
  int t = blockIdx.x, ti = 0;
  while (t >= 8 - ti){ t -= (8 - ti); ti++; }
  const int tj = ti + t;
  const int n0 = ti*128, m0 = tj*128;
  const int tid = threadIdx.x;
  const int tx = tid & 15, ty = tid >> 4;
  const float* xb = xin + (size_t)b*NN*rs;
  float acc[8][8];
#pragma unroll
  for (int i = 0; i < 8; i++)
#pragma unroll
    for (int j = 0; j < 8; j++) acc[i][j] = 0.f;

  const int nf4 = CT >> 2;
  for (int c0 = 0; c0 < Cin; c0 += CT){
    for (int e = tid; e < 128*nf4; e += 256){
      int r = e >> lnf4, cc = (e & (nf4-1))*4;
      *(float4*)(As + r*pitch + cc) = ld4(xb + (size_t)(n0+r)*rs + c0 + cc);
      *(float4*)(Bs + r*pitch + cc) = ld4(xb + (size_t)(m0+r)*rs + c0 + cc);
    }
    __syncthreads();
    for (int c = 0; c < CT; c += 4){
      float4 a[8], bv[8];
#pragma unroll
      for (int i = 0; i < 8; i++) a[i]  = ld4(As + (ty+16*i)*pitch + c);
#pragma unroll
      for (int j = 0; j < 8; j++) bv[j] = ld4(Bs + (tx+16*j)*pitch + c);
#pragma unroll
      for (int i = 0; i < 8; i++)
#pragma unroll
        for (int j = 0; j < 8; j++){
          acc[i][j] = fmaf(a[i].x, bv[j].x, acc[i][j]);
          acc[i][j] = fmaf(a[i].y, bv[j].y, acc[i][j]);
          acc[i][j] = fmaf(a[i].z, bv[j].z, acc[i][j]);
          acc[i][j] = fmaf(a[i].w, bv[j].w, acc[i][j]);
        }
    }
    __syncthreads();
  }

#pragma unroll
  for (int i = 0; i < 8; i++){
    int n = n0 + ty + 16*i;
#pragma unroll
    for (int j = 0; j < 8; j++){
      int m = m0 + tx + 16*j;
      pd[((size_t)b*NN + n)*NN + m] = 2.f*acc[i][j] - sq[b*NN + m];
    }
  }

  if (ti != tj){
    const int PT = 132;
    float* Ltr = lds;
    float sqn[8];
#pragma unroll
    for (int i = 0; i < 8; i++) sqn[i] = sq[b*NN + n0 + ty + 16*i];
#pragma unroll
    for (int h = 0; h < 2; h++){
      __syncthreads();
#pragma unroll
      for (int i = 0; i < 8; i++)
#pragma unroll
        for (int j = 4*h; j < 4*h+4; j++)
          Ltr[(tx + 16*j - 64*h)*PT + ty + 16*i] = 2.f*acc[i][j] - sqn[i];
      __syncthreads();
      for (int e = tid; e < 64*32; e += 256){
        int r = e >> 5, c4 = (e & 31)*4;
        *(float4*)(pd + ((size_t)b*NN + m0 + 64*h + r)*NN + n0 + c4) = *(float4*)(Ltr + r*PT + c4);
      }
    }
  }
}

// ------------ top-k v5 (k=20): per-lane sorted top-3 cache, 2 rows/wave ------------
// common path per extraction: butterfly + ballot + branchless cache pop. Rescan (reload
// from L2-hot pd, excluding killed bitmask) only when a lane has supplied 3 winners.
// tie semantics match jax.lax.top_k: value desc, index asc.
__global__ __launch_bounds__(256) void k_topk(const float* __restrict__ pd, int* __restrict__ idxOut){
  int w = threadIdx.x >> 6, lane = threadIdx.x & 63;
  int bn0 = (blockIdx.x*4 + w)*2;
  const float* row0 = pd + (size_t)bn0*NN + lane*16;
  const float* row1 = row0 + NN;

  float c0v[2], c1v[2], c2v[2];
  int   c0i[2], c1i[2], c2i[2];
  int   km[2] = {0, 0};
  top3_build(row0, 0, c0v[0], c1v[0], c2v[0], c0i[0], c1i[0], c2i[0]);
  top3_build(row1, 0, c0v[1], c1v[1], c2v[1], c0i[1], c1i[1], c2i[1]);

  int* out0 = idxOut + (size_t)bn0*KNN;
  int* out1 = out0 + KNN;
  for (int it = 0; it < KNN; it++){
    float g0 = c0v[0], g1 = c0v[1];
#pragma unroll
    for (int s = 1; s < 64; s <<= 1){
      g0 = fmaxf(g0, __shfl_xor(g0, s));
      g1 = fmaxf(g1, __shfl_xor(g1, s));
    }
    int o0 = __ffsll(__ballot(c0v[0] == g0)) - 1;
    int o1 = __ffsll(__ballot(c0v[1] == g1)) - 1;
    bool u0 = (lane == o0), u1 = (lane == o1);
    if (u0) out0[it] = lane*16 + c0i[0];
    if (u1) out1[it] = lane*16 + c0i[1];
    km[0] |= u0 ? (1 << c0i[0]) : 0;
    km[1] |= u1 ? (1 << c0i[1]) : 0;
    c0v[0] = u0 ? c1v[0] : c0v[0];  c0i[0] = u0 ? c1i[0] : c0i[0];
    c1v[0] = u0 ? c2v[0] : c1v[0];  c1i[0] = u0 ? c2i[0] : c1i[0];
    c2v[0] = u0 ? -1e30f : c2v[0];
    c0v[1] = u1 ? c1v[1] : c0v[1];  c0i[1] = u1 ? c1i[1] : c0i[1];
    c1v[1] = u1 ? c2v[1] : c1v[1];  c1i[1] = u1 ? c2i[1] : c1i[1];
    c2v[1] = u1 ? -1e30f : c2v[1];
    if (it < KNN-1){
      bool rp0 = (c0v[0] == -1e30f) && (km[0] != 0xFFFF);
      bool rp1 = (c0v[1] == -1e30f) && (km[1] != 0xFFFF);
      if (__ballot(rp0 || rp1)){            // wave-uniform skip in the common case
        if (rp0) top3_build(row0, km[0], c0v[0], c1v[0], c2v[0], c0i[0], c1i[0], c2i[0]);
        if (rp1) top3_build(row1, km[1], c0v[1], c1v[1], c2v[1], c0i[1], c1i[1], c2i[1]);
      }
    }
  }
}

// ---------------- L1 U|V: Z[n][0..63]=xt_n*wlT1, Z[n][64..127]=xt_n*dT1 (fp32, K=4) --------
__global__ __launch_bounds__(256) void k_uv1(const float* __restrict__ xt,
                                             const float* __restrict__ wlT, const float* __restrict__ dT,
                                             float* __restrict__ Z){
  int t = blockIdx.x*256 + threadIdx.x;
  int n = t >> 5, q = t & 31;
  float4 xv = ld4(xt + (size_t)n*4);
  const float* wp = (q < 16) ? (wlT + q*4) : (dT + (q-16)*4);
  float4 a = make_float4(0.f,0.f,0.f,0.f);
  fma4(a, xv.x, ld4(wp + 0*64));
  fma4(a, xv.y, ld4(wp + 1*64));
  fma4(a, xv.z, ld4(wp + 2*64));
  fma4(a, xv.w, ld4(wp + 3*64));
  *(float4*)(Z + (size_t)n*128 + q*4) = a;
}

// ---------------- U|V dense GEMM (bf16 MFMA) ----------------
template<int K>
__global__ __launch_bounds__(256) void k_uv(const unsigned short* __restrict__ hbi,
                                            const unsigned short* __restrict__ wB,
                                            float* __restrict__ Z, int ldz){
  __shared__ char sm[20480];
  char* As = sm; char* Bs = sm + 10240;
  const int tid = threadIdx.x, lane = tid & 63, w = tid >> 6;
  const int l15 = lane & 15, quad = lane >> 4;
  const int n0 = blockIdx.x*128, r0 = blockIdx.y*128;

  f32x4 acc[2][8];
  f32x4 zero = {0.f,0.f,0.f,0.f};
#pragma unroll
  for (int i = 0; i < 2; i++)
#pragma unroll
    for (int j = 0; j < 8; j++) acc[i][j] = zero;

  for (int k0 = 0; k0 < K; k0 += 32){
#pragma unroll
    for (int i = 0; i < 2; i++){
      int e = tid + i*256;
      int r = e >> 2, sg = e & 3;
      *(float4*)(As + r*80 + sg*16) = *(const float4*)(hbi + ((size_t)(r0+r))*512 + k0 + sg*8);
      *(float4*)(Bs + r*80 + sg*16) = *(const float4*)(wB  + ((size_t)(n0+r))*K   + k0 + sg*8);
    }
    __syncthreads();
    short8 af0 = *(short8*)(As + (w*32 + l15)*80 + quad*16);
    short8 af1 = *(short8*)(As + (w*32 + 16 + l15)*80 + quad*16);
#pragma unroll
    for (int ns = 0; ns < 8; ns++){
      short8 bf = *(short8*)(Bs + (ns*16 + l15)*80 + quad*16);
      acc[0][ns] = mfma16(af0, bf, acc[0][ns]);
      acc[1][ns] = mfma16(af1, bf, acc[1][ns]);
    }
    __syncthreads();
  }

#pragma unroll
  for (int ms = 0; ms < 2; ms++){
#pragma unroll
    for (int ns = 0; ns < 8; ns++){
      f32x4 a = acc[ms][ns];
      int row = r0 + w*32 + ms*16 + quad*4;
      int col = n0 + ns*16 + l15;
#pragma unroll
      for (int r = 0; r < 4; r++)
        Z[(size_t)(row+r)*ldz + col] = a[r];
    }
  }
}

// ---------------- gather-max ----------------
template<int COUT, int P, bool WF32>
__global__ __launch_bounds__(256) void k_gmax(const float* __restrict__ Z,
                                              const float* __restrict__ bias,
                                              const int* __restrict__ knn_idx,
                                              float* __restrict__ hf,
                                              unsigned short* __restrict__ hbo){
  constexpr int QPP = COUT/4;
  __shared__ int idxS[P*KNN];
  const int tid = threadIdx.x;
  const int p0 = blockIdx.x * P;
  for (int t = tid; t < P*KNN; t += 256) idxS[t] = knn_idx[(size_t)p0*KNN + t];
  __syncthreads();

  const int p = tid / QPP, q = tid - p*QPP;
  const int base = p0 & ~1023;
  const int ldz = 2*COUT;
  const float* Zq = Z + q*4;

  float4 m = make_float4(-1e30f,-1e30f,-1e30f,-1e30f);
#pragma unroll
  for (int j = 0; j < KNN; j++){
    int mr = idxS[p*KNN + j];
    max4(m, ld4(Zq + (size_t)(base + mr)*ldz));
  }
  float4 ctr = ld4(Z + (size_t)(p0+p)*ldz + COUT + q*4);
  float4 bs  = ld4(bias + q*4);
  float4 y;
  y.x = m.x + ctr.x + bs.x; y.x = fmaxf(y.x, 0.2f*y.x);
  y.y = m.y + ctr.y + bs.y; y.y = fmaxf(y.y, 0.2f*y.y);
  y.z = m.z + ctr.z + bs.z; y.z = fmaxf(y.z, 0.2f*y.z);
  y.w = m.w + ctr.w + bs.w; y.w = fmaxf(y.w, 0.2f*y.w);

  size_t pi = (size_t)(p0 + p);
  if (WF32) *(float4*)(hf + pi*256 + q*4) = y;
  ushort4 hv; hv.x = f2bf(y.x); hv.y = f2bf(y.y); hv.z = f2bf(y.z); hv.w = f2bf(y.w);
  *(ushort4*)(hbo + pi*512 + q*4) = hv;
}

// ---------------- conv5 (bf16 MFMA) + bias + lrelu + partial pool ----------------
__global__ __launch_bounds__(256) void k_conv5m(const unsigned short* __restrict__ hb,
                                                const unsigned short* __restrict__ w5b,
                                                const float* __restrict__ b5,
                                                float* __restrict__ pmax, float* __restrict__ psum){
  __shared__ char sm[20480 + 4096];
  char* As = sm; char* Bs = sm + 10240;
  float* red = (float*)(sm + 20480);
  const int tid = threadIdx.x, lane = tid & 63, w = tid >> 6;
  const int l15 = lane & 15, quad = lane >> 4;
  const int n0 = blockIdx.x*128, r0 = blockIdx.y*128;

  f32x4 acc[2][8];
  f32x4 zero = {0.f,0.f,0.f,0.f};
#pragma unroll
  for (int i = 0; i < 2; i++)
#pragma unroll
    for (int j = 0; j < 8; j++) acc[i][j] = zero;

  for (int k0 = 0; k0 < 512; k0 += 32){
#pragma unroll
    for (int i = 0; i < 2; i++){
      int e = tid + i*256;
      int r = e >> 2, sg = e & 3;
      *(float4*)(As + r*80 + sg*16) = *(const float4*)(hb  + ((size_t)(r0+r))*512 + k0 + sg*8);
      *(float4*)(Bs + r*80 + sg*16) = *(const float4*)(w5b + ((size_t)(n0+r))*512 + k0 + sg*8);
    }
    __syncthreads();
    short8 af0 = *(short8*)(As + (w*32 + l15)*80 + quad*16);
    short8 af1 = *(short8*)(As + (w*32 + 16 + l15)*80 + quad*16);
#pragma unroll
    for (int ns = 0; ns < 8; ns++){
      short8 bf = *(short8*)(Bs + (ns*16 + l15)*80 + quad*16);
      acc[0][ns] = mfma16(af0, bf, acc[0][ns]);
      acc[1][ns] = mfma16(af1, bf, acc[1][ns]);
    }
    __syncthreads();
  }

#pragma unroll
  for (int ns = 0; ns < 8; ns++){
    float bv = b5[n0 + ns*16 + l15];
    float mx = -1e30f, sum = 0.f;
#pragma unroll
    for (int ms = 0; ms < 2; ms++){
      float* a = (float*)&acc[ms][ns];
#pragma unroll
      for (int r = 0; r < 4; r++){
        float v = a[r] + bv; v = fmaxf(v, 0.2f*v);
        mx = fmaxf(mx, v); sum += v;
      }
    }
    for (int s = 16; s < 64; s <<= 1){
      mx = fmaxf(mx, __shfl_xor(mx, s));
      sum += __shfl_xor(sum, s);
    }
    if (quad == 0){ red[(w*8 + ns)*16 + l15] = mx; red[512 + (w*8 + ns)*16 + l15] = sum; }
  }
  __syncthreads();
  if (tid < 128){
    int ns = tid >> 4, ci = tid & 15;
    float mx = -1e30f, sum = 0.f;
#pragma unroll
    for (int w2 = 0; w2 < 4; w2++){
      mx = fmaxf(mx, red[(w2*8 + ns)*16 + ci]);
      sum += red[512 + (w2*8 + ns)*16 + ci];
    }
    pmax[(size_t)blockIdx.y*1024 + n0 + tid] = mx;
    psum[(size_t)blockIdx.y*1024 + n0 + tid] = sum;
  }
}

// ---------------- FC1: 2048->512, pool fused (max/mean over 8 chunks) ----------------
__global__ __launch_bounds__(256) void k_fc1(const float* __restrict__ pmax, const float* __restrict__ psum,
                                             const float* __restrict__ wl1, const float* __restrict__ bn6,
                                             float* __restrict__ h1){
  __shared__ float pS[2048];
  const int b = blockIdx.y, t = threadIdx.x;
  for (int f = t; f < 512; f += 256){
    float4 r;
    if (f < 256){
      r = ld4(pmax + (size_t)(b*8)*1024 + f*4);
#pragma unroll
      for (int ch = 1; ch < 8; ch++) max4(r, ld4(pmax + (size_t)(b*8+ch)*1024 + f*4));
    } else {
      int o = (f-256)*4;
      r = ld4(psum + (size_t)(b*8)*1024 + o);
#pragma unroll
      for (int ch = 1; ch < 8; ch++){
        float4 s = ld4(psum + (size_t)(b*8+ch)*1024 + o);
        r.x += s.x; r.y += s.y; r.z += s.z; r.w += s.w;
      }
      r.x *= (1.f/1024.f); r.y *= (1.f/1024.f); r.z *= (1.f/1024.f); r.w *= (1.f/1024.f);
    }
    ((float4*)pS)[f] = r;
  }
  __syncthreads();
  const int ol = t >> 4, ch = t & 15;
  const int o = blockIdx.x*16 + ol;
  const float* wr = wl1 + (size_t)o*2048;
  float acc = 0.f;
#pragma unroll
  for (int j = 0; j < 32; j++){
    int c = ch*4 + j*64;
    float4 wv = ld4(wr + c);
    acc += pS[c]*wv.x + pS[c+1]*wv.y + pS[c+2]*wv.z + pS[c+3]*wv.w;
  }
#pragma unroll
  for (int s = 1; s < 16; s <<= 1) acc += __shfl_xor(acc, s);
  if (ch == 0){
    float s = bn6[o] * rsqrtf(bn6[3*512+o] + BNEPS);
    float y = (acc - bn6[2*512+o])*s + bn6[512+o];
    h1[(size_t)b*512 + o] = fmaxf(y, 0.2f*y);
  }
}

// ---------------- FC2: 512->256 ----------------
__global__ __launch_bounds__(256) void k_fc2(const float* __restrict__ h1,
                                             const float* __restrict__ wl2, const float* __restrict__ bn7,
                                             float* __restrict__ h2){
  __shared__ float hS[512];
  const int b = blockIdx.y, t = threadIdx.x;
  if (t < 128) ((float4*)hS)[t] = ((const float4*)(h1 + (size_t)b*512))[t];
  __syncthreads();
  const int ol = t >> 4, ch = t & 15;
  const int o = blockIdx.x*16 + ol;
  const float* wr = wl2 + (size_t)o*512;
  float acc = 0.f;
#pragma unroll
  for (int j = 0; j < 8; j++){
    int c = ch*4 + j*64;
    float4 wv = ld4(wr + c);
    acc += hS[c]*wv.x + hS[c+1]*wv.y + hS[c+2]*wv.z + hS[c+3]*wv.w;
  }
#pragma unroll
  for (int s = 1; s < 16; s <<= 1) acc += __shfl_xor(acc, s);
  if (ch == 0){
    float s = bn7[o] * rsqrtf(bn7[3*256+o] + BNEPS);
    float y = (acc - bn7[2*256+o])*s + bn7[256+o];
    h2[(size_t)b*256 + o] = fmaxf(y, 0.2f*y);
  }
}

// ---------------- FC3: 256->40 ----------------
__global__ __launch_bounds__(64) void k_fc3(const float* __restrict__ h2,
                                            const float* __restrict__ wl3, const float* __restrict__ bl3,
                                            float* __restrict__ out){
  const int o = blockIdx.x, b = blockIdx.y, lane = threadIdx.x;
  float4 wv = ld4(wl3 + (size_t)o*256 + lane*4);
  float4 hv = ld4(h2 + (size_t)b*256 + lane*4);
  float acc = hv.x*wv.x + hv.y*wv.y + hv.z*wv.z + hv.w*wv.w;
#pragma unroll
  for (int s = 1; s < 64; s <<= 1) acc += __shfl_xor(acc, s);
  if (lane == 0) out[(size_t)b*40 + o] = acc + bl3[o];
}

extern "C" void kernel_launch(void* const* d_in, const int* in_sizes, int n_in,
                              void* d_out, int out_size, void* d_ws, size_t ws_size,
                              hipStream_t stream) {
  (void)in_sizes; (void)n_in; (void)out_size; (void)ws_size;
  const float* x   = (const float*)d_in[0];
  const float* w1  = (const float*)d_in[1];
  const float* bn1 = (const float*)d_in[2];
  const float* w2  = (const float*)d_in[3];
  const float* bn2 = (const float*)d_in[4];
  const float* w3  = (const float*)d_in[5];
  const float* bn3 = (const float*)d_in[6];
  const float* w4  = (const float*)d_in[7];
  const float* bn4 = (const float*)d_in[8];
  const float* w5  = (const float*)d_in[9];
  const float* bn5 = (const float*)d_in[10];
  const float* wl1 = (const float*)d_in[11];
  const float* bn6 = (const float*)d_in[12];
  const float* wl2 = (const float*)d_in[13];
  const float* bn7 = (const float*)d_in[14];
  const float* wl3 = (const float*)d_in[15];
  const float* bl3 = (const float*)d_in[16];
  float* out = (float*)d_out;

  float* ws    = (float*)d_ws;
  float* xt    = ws;                          // 65536
  float* sqb   = xt + 65536;                  // 16384
  int*   idxb  = (int*)(sqb + 16384);         // 327680 ints
  float* pd    = (float*)(idxb + 327680);     // 16777216 (Z aliases, used after topk)
  float* h     = pd + 16777216;               // 4194304 (fp32 acts, stride 256)
  float* wlT1  = h + 4194304;                 // 256
  float* dT1   = wlT1 + 256;                  // 256
  float* bias1 = dT1 + 256;                   // 64
  float* bias2 = bias1 + 64;                  // 64
  float* bias3 = bias2 + 64;                  // 128
  float* bias4 = bias3 + 128;                 // 256
  float* b5    = bias4 + 256;                 // 1024
  float* pmax  = b5 + 1024;                   // 131072
  float* psum  = pmax + 131072;               // 131072
  float* pool  = psum + 131072;               // 32768 (unused; layout kept)
  float* h1b   = pool + 32768;                // 8192
  float* h2b   = h1b + 8192;                  // 4096
  unsigned short* hb   = (unsigned short*)(h2b + 4096);    // 16384*512 bf16
  unsigned short* wlB2 = hb + (size_t)16384*512;            // 4096 (dB2 contiguous after)
  unsigned short* dB2  = wlB2 + 4096;
  unsigned short* wlB3 = dB2 + 4096;                        // 8192 (dB3 contiguous)
  unsigned short* dB3  = wlB3 + 8192;
  unsigned short* wlB4 = dB3 + 8192;                        // 32768 (dB4 contiguous)
  unsigned short* dB4  = wlB4 + 32768;
  unsigned short* w5b  = dB4 + 32768;                       // 524288
  float* Z = pd;

  k_transpose<<<64, 256, 0, stream>>>(x, xt, sqb);
  k_prep_all<<<2225, 256, 0, stream>>>(w1, bn1, w2, bn2, w3, bn3, w4, bn4, w5, bn5,
                                       wlT1, dT1, bias1, wlB2, dB2, bias2,
                                       wlB3, dB3, bias3, wlB4, dB4, bias4, w5b, b5);

  const size_t PD_LDS32 = 36864;
  const size_t PD_LDS4  = 33792;

  // ---- L1 (Cin=4 -> Cout=64) ----
  k_pd<<<dim3(36,16), 256, PD_LDS4, stream>>>(xt, 4, 4, 4, 0, sqb, pd);
  k_topk<<<2048, 256, 0, stream>>>(pd, idxb);
  k_uv1<<<2048, 256, 0, stream>>>(xt, wlT1, dT1, Z);
  k_gmax<64,16,true><<<1024, 256, 0, stream>>>(Z, bias1, idxb, h, hb);

  // ---- L2 (64 -> 64) ----
  k_sq<<<64, 256, 0, stream>>>(h, 256, 64, sqb);
  k_pd<<<dim3(36,16), 256, PD_LDS32, stream>>>(h, 256, 64, 32, 3, sqb, pd);
  k_topk<<<2048, 256, 0, stream>>>(pd, idxb);
  k_uv<64><<<dim3(1,128), 256, 0, stream>>>(hb, wlB2, Z, 128);
  k_gmax<64,16,true><<<1024, 256, 0, stream>>>(Z, bias2, idxb, h + 64, hb + 64);

  // ---- L3 (64 -> 128) ----
  k_sq<<<64, 256, 0, stream>>>(h + 64, 256, 64, sqb);
  k_pd<<<dim3(36,16), 256, PD_LDS32, stream>>>(h + 64, 256, 64, 32, 3, sqb, pd);
  k_topk<<<2048, 256, 0, stream>>>(pd, idxb);
  k_uv<64><<<dim3(2,128), 256, 0, stream>>>(hb + 64, wlB3, Z, 256);
  k_gmax<128,8,true><<<2048, 256, 0, stream>>>(Z, bias3, idxb, h + 128, hb + 128);

  // ---- L4 (128 -> 256; bf16 out only) ----
  k_sq<<<64, 256, 0, stream>>>(h + 128, 256, 128, sqb);
  k_pd<<<dim3(36,16), 256, PD_LDS32, stream>>>(h + 128, 256, 128, 32, 3, sqb, pd);
  k_topk<<<2048, 256, 0, stream>>>(pd, idxb);
  k_uv<128><<<dim3(4,128), 256, 0, stream>>>(hb + 128, wlB4, Z, 512);
  k_gmax<256,4,false><<<4096, 256, 0, stream>>>(Z, bias4, idxb, nullptr, hb + 256);

  // ---- conv5 + FC head (pool fused into fc1) ----
  k_conv5m<<<dim3(8,128), 256, 0, stream>>>(hb, w5b, b5, pmax, psum);
  k_fc1<<<dim3(32,16), 256, 0, stream>>>(pmax, psum, wl1, bn6, h1b);
  k_fc2<<<dim3(16,16), 256, 0, stream>>>(h1b, wl2, bn7, h2b);
  k_fc3<<<dim3(40,16), 64, 0, stream>>>(h2b, wl3, bl3, out);
}

// Round 15
// 464.901 us; speedup vs baseline: 1.3081x; 1.0229x over previous
//
#include <hip/hip_runtime.h>

#define BB 16
#define NN 1024
#define KNN 20
#define BNEPS 1e-5f

typedef __attribute__((ext_vector_type(8))) short short8;
typedef __attribute__((ext_vector_type(4))) float f32x4;

__device__ __forceinline__ float4 ld4(const float* p){ return *(const float4*)p; }
__device__ __forceinline__ void fma4(float4& a, float s, float4 w){
  a.x = fmaf(s, w.x, a.x); a.y = fmaf(s, w.y, a.y);
  a.z = fmaf(s, w.z, a.z); a.w = fmaf(s, w.w, a.w);
}
__device__ __forceinline__ void max4(float4& a, float4 v){
  a.x = fmaxf(a.x, v.x); a.y = fmaxf(a.y, v.y);
  a.z = fmaxf(a.z, v.z); a.w = fmaxf(a.w, v.w);
}
__device__ __forceinline__ unsigned short f2bf(float f){
  unsigned int u = __float_as_uint(f);
  u = (u + 0x7FFF + ((u >> 16) & 1)) >> 16;   // RNE, finite inputs
  return (unsigned short)u;
}
__device__ __forceinline__ f32x4 mfma16(short8 a, short8 b, f32x4 c){
  return __builtin_amdgcn_mfma_f32_16x16x32_bf16(a, b, c, 0, 0, 0);
}

// build exact (value desc, index asc) top-3 of a lane's 16 row elements, excluding km bits
__device__ __forceinline__ void top3_build(const float* rp, int kmr,
                                           float& a0, float& a1, float& a2,
                                           int& i0, int& i1, int& i2){
  a0 = -1e30f; a1 = -1e30f; a2 = -1e30f; i0 = 0; i1 = 0; i2 = 0;
#pragma unroll
  for (int r = 0; r < 4; r++){
    float4 t = ld4(rp + r*4);
    float tv[4] = {t.x, t.y, t.z, t.w};
#pragma unroll
    for (int q = 0; q < 4; q++){
      int e = r*4 + q;
      float v = ((kmr >> e) & 1) ? -1e30f : tv[q];
      bool b0 = v > a0, b1 = v > a1, b2 = v > a2;
      a2 = b1 ? a1 : (b2 ? v : a2); i2 = b1 ? i1 : (b2 ? e : i2);
      a1 = b0 ? a0 : (b1 ? v : a1); i1 = b0 ? i0 : (b1 ? e : i1);
      a0 = b0 ? v  : a0;            i0 = b0 ? e : i0;
    }
  }
}

// ---------------- transpose x (B,3,N) -> xt (B,N,4) padded; also sq for L1 ----------------
__global__ __launch_bounds__(256) void k_transpose(const float* __restrict__ x, float* __restrict__ xt,
                                                   float* __restrict__ sq){
  int i = blockIdx.x*256 + threadIdx.x;
  if (i >= BB*NN) return;
  int b = i >> 10, n = i & 1023;
  const float* xb = x + (size_t)b*3*NN;
  float4 v;
  v.x = xb[0*NN+n]; v.y = xb[1*NN+n]; v.z = xb[2*NN+n]; v.w = 0.f;
  ((float4*)xt)[i] = v;
  sq[i] = v.x*v.x + v.y*v.y + v.z*v.z;
}

// ---- device preps ----
__device__ __forceinline__ void prep_w_dev(int i, const float* w, const float* bnp,
                                           float* wlT, float* dT, float* bias, int Cin, int Cpad, int Cout){
  if (i >= Cpad*Cout) return;
  int c = i / Cout, o = i - c*Cout;
  float s = bnp[o] * rsqrtf(bnp[3*Cout+o] + BNEPS);
  float wl = (c < Cin) ? w[(size_t)o*2*Cin + c] : 0.f;
  float wr = (c < Cin) ? w[(size_t)o*2*Cin + Cin + c] : 0.f;
  wlT[i] = wl * s;
  dT[i]  = (wr - wl) * s;
  if (c == 0) bias[o] = bnp[Cout+o] - bnp[2*Cout+o]*s;
}
__device__ __forceinline__ void prep_wbf_dev(int i, const float* w, const float* bnp,
                                             unsigned short* wlB, unsigned short* dB, float* bias,
                                             int Cin, int Cout){
  if (i >= Cin*Cout) return;
  int o = i / Cin, c = i - o*Cin;
  float s = bnp[o] * rsqrtf(bnp[3*Cout+o] + BNEPS);
  float wl = w[(size_t)o*2*Cin + c] * s;
  float wr = w[(size_t)o*2*Cin + Cin + c] * s;
  wlB[i] = f2bf(wl);
  dB[i]  = f2bf(wr - wl);
  if (c == 0) bias[o] = bnp[Cout+o] - bnp[2*Cout+o]*s;
}

// ---- single merged prep kernel ----
__global__ __launch_bounds__(256) void k_prep_all(const float* __restrict__ w1, const float* __restrict__ bn1,
                                                  const float* __restrict__ w2, const float* __restrict__ bn2,
                                                  const float* __restrict__ w3, const float* __restrict__ bn3,
                                                  const float* __restrict__ w4, const float* __restrict__ bn4,
                                                  const float* __restrict__ w5, const float* __restrict__ bn5,
                                                  float* __restrict__ wlT1, float* __restrict__ dT1, float* __restrict__ bias1,
                                                  unsigned short* __restrict__ wlB2, unsigned short* __restrict__ dB2, float* __restrict__ bias2,
                                                  unsigned short* __restrict__ wlB3, unsigned short* __restrict__ dB3, float* __restrict__ bias3,
                                                  unsigned short* __restrict__ wlB4, unsigned short* __restrict__ dB4, float* __restrict__ bias4,
                                                  unsigned short* __restrict__ w5b, float* __restrict__ b5){
  int bid = blockIdx.x, t = threadIdx.x;
  if (bid < 1){
    prep_w_dev(t, w1, bn1, wlT1, dT1, bias1, 3, 4, 64);
  } else if (bid < 17){
    prep_wbf_dev((bid-1)*256 + t, w2, bn2, wlB2, dB2, bias2, 64, 64);
  } else if (bid < 49){
    prep_wbf_dev((bid-17)*256 + t, w3, bn3, wlB3, dB3, bias3, 64, 128);
  } else if (bid < 177){
    prep_wbf_dev((bid-49)*256 + t, w4, bn4, wlB4, dB4, bias4, 128, 256);
  } else {
    int i = (bid-177)*256 + t;
    int o = i >> 9, c = i & 511;
    float s = bn5[o] * rsqrtf(bn5[3*1024+o] + BNEPS);
    w5b[i] = f2bf(w5[(size_t)o*512 + c] * s);
    if (c == 0) b5[o] = bn5[1024+o] - bn5[2*1024+o]*s;
  }
}

// ---------------- sq[b*N+n] = sum_c in[n][c]^2 (L2-L4) ----------------
__global__ __launch_bounds__(256) void k_sq(const float* __restrict__ xin, int rs, int Cin, float* __restrict__ sq){
  int i = blockIdx.x*256 + threadIdx.x;
  if (i >= BB*NN) return;
  const float* r = xin + (size_t)i*rs;
  float s = 0.f;
  for (int c = 0; c < Cin; c += 4){
    float4 v = ld4(r + c);
    s += v.x*v.x + v.y*v.y + v.z*v.z + v.w*v.w;
  }
  sq[i] = s;
}

// -------- pd symmetric v2: 64x64 upper-triangle tiles (136/batch -> 2176 blocks) --------
// 4x4 acc/thread, CT up to 64 (single staging barrier pair per K-chunk).
// off-diagonal tiles also write transposed tile via LDS (pitch 68, 2-way = free).
__global__ __launch_bounds__(256) void k_pd(const float* __restrict__ xin, int rs, int Cin, int CT, int lnf4,
                                            const float* __restrict__ sq, float* __restrict__ pd){
  extern __shared__ float lds[];
  const int pitch = CT + 4;
  float* As = lds;
  float* Bs = lds + 64*pitch;
  const int b = blockIdx.y;
  int t = blockIdx.x, ti = 0;
  while (t >= 16 - ti){ t -= (16 - ti); ti++; }
  const int tj = ti + t;
  const int n0 = ti*64, m0 = tj*64;
  const int tid = threadIdx.x;
  const int tx = tid & 15, ty = tid >> 4;
  const float* xb = xin + (size_t)b*NN*rs;
  float acc[4][4];
#pragma unroll
  for (int i = 0; i < 4; i++)
#pragma unroll
    for (int j = 0; j < 4; j++) acc[i][j] = 0.f;

  const int nf4 = CT >> 2;
  for (int c0 = 0; c0 < Cin; c0 += CT){
    for (int e = tid; e < 64*nf4; e += 256){
      int r = e >> lnf4, cc = (e & (nf4-1))*4;
      *(float4*)(As + r*pitch + cc) = ld4(xb + (size_t)(n0+r)*rs + c0 + cc);
      *(float4*)(Bs + r*pitch + cc) = ld4(xb + (size_t)(m0+r)*rs + c0 + cc);
    }
    __syncthreads();
    for (int c = 0; c < CT; c += 4){
      float4 a[4], bv[4];
#pragma unroll
      for (int i = 0; i < 4; i++) a[i]  = ld4(As + (ty+16*i)*pitch + c);
#pragma unroll
      for (int j = 0; j < 4; j++) bv[j] = ld4(Bs + (tx+16*j)*pitch + c);
#pragma unroll
      for (int i = 0; i < 4; i++)
#pragma unroll
        for (int j = 0; j < 4; j++){
          acc[i][j] = fmaf(a[i].x, bv[j].x, acc[i][j]);
          acc[i][j] = fmaf(a[i].y, bv[j].y, acc[i][j]);
          acc[i][j] = fmaf(a[i].z, bv[j].z, acc[i][j]);
          acc[i][j] = fmaf(a[i].w, bv[j].w, acc[i][j]);
        }
    }
    __syncthreads();
  }

  // direct write: pd[n][m] = 2*acc - sq[m]  (coalesced)
#pragma unroll
  for (int i = 0; i < 4; i++){
    int n = n0 + ty + 16*i;
#pragma unroll
    for (int j = 0; j < 4; j++){
      int m = m0 + tx + 16*j;
      pd[((size_t)b*NN + n)*NN + m] = 2.f*acc[i][j] - sq[b*NN + m];
    }
  }

  // transposed write for off-diagonal tiles: pd[m][n] = 2*acc - sq[n]
  if (ti != tj){
    const int PT = 68;
    float* Ltr = lds;                  // reuse staging (all reads done, synced above)
    float sqn[4];
#pragma unroll
    for (int i = 0; i < 4; i++) sqn[i] = sq[b*NN + n0 + ty + 16*i];
#pragma unroll
    for (int i = 0; i < 4; i++)
#pragma unroll
      for (int j = 0; j < 4; j++)
        Ltr[(tx + 16*j)*PT + ty + 16*i] = 2.f*acc[i][j] - sqn[i];
    __syncthreads();
    for (int e = tid; e < 64*16; e += 256){
      int r = e >> 4, c4 = (e & 15)*4;
      *(float4*)(pd + ((size_t)b*NN + m0 + r)*NN + n0 + c4) = *(float4*)(Ltr + r*PT + c4);
    }
  }
}

// ------------ top-k v5 (k=20): per-lane sorted top-3 cache, 2 rows/wave ------------
__global__ __launch_bounds__(256) void k_topk(const float* __restrict__ pd, int* __restrict__ idxOut){
  int w = threadIdx.x >> 6, lane = threadIdx.x & 63;
  int bn0 = (blockIdx.x*4 + w)*2;
  const float* row0 = pd + (size_t)bn0*NN + lane*16;
  const float* row1 = row0 + NN;

  float c0v[2], c1v[2], c2v[2];
  int   c0i[2], c1i[2], c2i[2];
  int   km[2] = {0, 0};
  top3_build(row0, 0, c0v[0], c1v[0], c2v[0], c0i[0], c1i[0], c2i[0]);
  top3_build(row1, 0, c0v[1], c1v[1], c2v[1], c0i[1], c1i[1], c2i[1]);

  int* out0 = idxOut + (size_t)bn0*KNN;
  int* out1 = out0 + KNN;
  for (int it = 0; it < KNN; it++){
    float g0 = c0v[0], g1 = c0v[1];
#pragma unroll
    for (int s = 1; s < 64; s <<= 1){
      g0 = fmaxf(g0, __shfl_xor(g0, s));
      g1 = fmaxf(g1, __shfl_xor(g1, s));
    }
    int o0 = __ffsll(__ballot(c0v[0] == g0)) - 1;
    int o1 = __ffsll(__ballot(c0v[1] == g1)) - 1;
    bool u0 = (lane == o0), u1 = (lane == o1);
    if (u0) out0[it] = lane*16 + c0i[0];
    if (u1) out1[it] = lane*16 + c0i[1];
    km[0] |= u0 ? (1 << c0i[0]) : 0;
    km[1] |= u1 ? (1 << c0i[1]) : 0;
    c0v[0] = u0 ? c1v[0] : c0v[0];  c0i[0] = u0 ? c1i[0] : c0i[0];
    c1v[0] = u0 ? c2v[0] : c1v[0];  c1i[0] = u0 ? c2i[0] : c1i[0];
    c2v[0] = u0 ? -1e30f : c2v[0];
    c0v[1] = u1 ? c1v[1] : c0v[1];  c0i[1] = u1 ? c1i[1] : c0i[1];
    c1v[1] = u1 ? c2v[1] : c1v[1];  c1i[1] = u1 ? c2i[1] : c1i[1];
    c2v[1] = u1 ? -1e30f : c2v[1];
    if (it < KNN-1){
      bool rp0 = (c0v[0] == -1e30f) && (km[0] != 0xFFFF);
      bool rp1 = (c0v[1] == -1e30f) && (km[1] != 0xFFFF);
      if (__ballot(rp0 || rp1)){
        if (rp0) top3_build(row0, km[0], c0v[0], c1v[0], c2v[0], c0i[0], c1i[0], c2i[0]);
        if (rp1) top3_build(row1, km[1], c0v[1], c1v[1], c2v[1], c0i[1], c1i[1], c2i[1]);
      }
    }
  }
}

// ---------------- L1 U|V: Z[n][0..63]=xt_n*wlT1, Z[n][64..127]=xt_n*dT1 (fp32, K=4) --------
__global__ __launch_bounds__(256) void k_uv1(const float* __restrict__ xt,
                                             const float* __restrict__ wlT, const float* __restrict__ dT,
                                             float* __restrict__ Z){
  int t = blockIdx.x*256 + threadIdx.x;
  int n = t >> 5, q = t & 31;
  float4 xv = ld4(xt + (size_t)n*4);
  const float* wp = (q < 16) ? (wlT + q*4) : (dT + (q-16)*4);
  float4 a = make_float4(0.f,0.f,0.f,0.f);
  fma4(a, xv.x, ld4(wp + 0*64));
  fma4(a, xv.y, ld4(wp + 1*64));
  fma4(a, xv.z, ld4(wp + 2*64));
  fma4(a, xv.w, ld4(wp + 3*64));
  *(float4*)(Z + (size_t)n*128 + q*4) = a;
}

// ---------------- U|V dense GEMM (bf16 MFMA) ----------------
template<int K>
__global__ __launch_bounds__(256) void k_uv(const unsigned short* __restrict__ hbi,
                                            const unsigned short* __restrict__ wB,
                                            float* __restrict__ Z, int ldz){
  __shared__ char sm[20480];
  char* As = sm; char* Bs = sm + 10240;
  const int tid = threadIdx.x, lane = tid & 63, w = tid >> 6;
  const int l15 = lane & 15, quad = lane >> 4;
  const int n0 = blockIdx.x*128, r0 = blockIdx.y*128;

  f32x4 acc[2][8];
  f32x4 zero = {0.f,0.f,0.f,0.f};
#pragma unroll
  for (int i = 0; i < 2; i++)
#pragma unroll
    for (int j = 0; j < 8; j++) acc[i][j] = zero;

  for (int k0 = 0; k0 < K; k0 += 32){
#pragma unroll
    for (int i = 0; i < 2; i++){
      int e = tid + i*256;
      int r = e >> 2, sg = e & 3;
      *(float4*)(As + r*80 + sg*16) = *(const float4*)(hbi + ((size_t)(r0+r))*512 + k0 + sg*8);
      *(float4*)(Bs + r*80 + sg*16) = *(const float4*)(wB  + ((size_t)(n0+r))*K   + k0 + sg*8);
    }
    __syncthreads();
    short8 af0 = *(short8*)(As + (w*32 + l15)*80 + quad*16);
    short8 af1 = *(short8*)(As + (w*32 + 16 + l15)*80 + quad*16);
#pragma unroll
    for (int ns = 0; ns < 8; ns++){
      short8 bf = *(short8*)(Bs + (ns*16 + l15)*80 + quad*16);
      acc[0][ns] = mfma16(af0, bf, acc[0][ns]);
      acc[1][ns] = mfma16(af1, bf, acc[1][ns]);
    }
    __syncthreads();
  }

#pragma unroll
  for (int ms = 0; ms < 2; ms++){
#pragma unroll
    for (int ns = 0; ns < 8; ns++){
      f32x4 a = acc[ms][ns];
      int row = r0 + w*32 + ms*16 + quad*4;
      int col = n0 + ns*16 + l15;
#pragma unroll
      for (int r = 0; r < 4; r++)
        Z[(size_t)(row+r)*ldz + col] = a[r];
    }
  }
}

// ---------------- gather-max ----------------
template<int COUT, int P, bool WF32>
__global__ __launch_bounds__(256) void k_gmax(const float* __restrict__ Z,
                                              const float* __restrict__ bias,
                                              const int* __restrict__ knn_idx,
                                              float* __restrict__ hf,
                                              unsigned short* __restrict__ hbo){
  constexpr int QPP = COUT/4;
  __shared__ int idxS[P*KNN];
  const int tid = threadIdx.x;
  const int p0 = blockIdx.x * P;
  for (int t = tid; t < P*KNN; t += 256) idxS[t] = knn_idx[(size_t)p0*KNN + t];
  __syncthreads();

  const int p = tid / QPP, q = tid - p*QPP;
  const int base = p0 & ~1023;
  const int ldz = 2*COUT;
  const float* Zq = Z + q*4;

  float4 m = make_float4(-1e30f,-1e30f,-1e30f,-1e30f);
#pragma unroll
  for (int j = 0; j < KNN; j++){
    int mr = idxS[p*KNN + j];
    max4(m, ld4(Zq + (size_t)(base + mr)*ldz));
  }
  float4 ctr = ld4(Z + (size_t)(p0+p)*ldz + COUT + q*4);
  float4 bs  = ld4(bias + q*4);
  float4 y;
  y.x = m.x + ctr.x + bs.x; y.x = fmaxf(y.x, 0.2f*y.x);
  y.y = m.y + ctr.y + bs.y; y.y = fmaxf(y.y, 0.2f*y.y);
  y.z = m.z + ctr.z + bs.z; y.z = fmaxf(y.z, 0.2f*y.z);
  y.w = m.w + ctr.w + bs.w; y.w = fmaxf(y.w, 0.2f*y.w);

  size_t pi = (size_t)(p0 + p);
  if (WF32) *(float4*)(hf + pi*256 + q*4) = y;
  ushort4 hv; hv.x = f2bf(y.x); hv.y = f2bf(y.y); hv.z = f2bf(y.z); hv.w = f2bf(y.w);
  *(ushort4*)(hbo + pi*512 + q*4) = hv;
}

// ---------------- conv5 (bf16 MFMA) + bias + lrelu + partial pool ----------------
__global__ __launch_bounds__(256) void k_conv5m(const unsigned short* __restrict__ hb,
                                                const unsigned short* __restrict__ w5b,
                                                const float* __restrict__ b5,
                                                float* __restrict__ pmax, float* __restrict__ psum){
  __shared__ char sm[20480 + 4096];
  char* As = sm; char* Bs = sm + 10240;
  float* red = (float*)(sm + 20480);
  const int tid = threadIdx.x, lane = tid & 63, w = tid >> 6;
  const int l15 = lane & 15, quad = lane >> 4;
  const int n0 = blockIdx.x*128, r0 = blockIdx.y*128;

  f32x4 acc[2][8];
  f32x4 zero = {0.f,0.f,0.f,0.f};
#pragma unroll
  for (int i = 0; i < 2; i++)
#pragma unroll
    for (int j = 0; j < 8; j++) acc[i][j] = zero;

  for (int k0 = 0; k0 < 512; k0 += 32){
#pragma unroll
    for (int i = 0; i < 2; i++){
      int e = tid + i*256;
      int r = e >> 2, sg = e & 3;
      *(float4*)(As + r*80 + sg*16) = *(const float4*)(hb  + ((size_t)(r0+r))*512 + k0 + sg*8);
      *(float4*)(Bs + r*80 + sg*16) = *(const float4*)(w5b + ((size_t)(n0+r))*512 + k0 + sg*8);
    }
    __syncthreads();
    short8 af0 = *(short8*)(As + (w*32 + l15)*80 + quad*16);
    short8 af1 = *(short8*)(As + (w*32 + 16 + l15)*80 + quad*16);
#pragma unroll
    for (int ns = 0; ns < 8; ns++){
      short8 bf = *(short8*)(Bs + (ns*16 + l15)*80 + quad*16);
      acc[0][ns] = mfma16(af0, bf, acc[0][ns]);
      acc[1][ns] = mfma16(af1, bf, acc[1][ns]);
    }
    __syncthreads();
  }

#pragma unroll
  for (int ns = 0; ns < 8; ns++){
    float bv = b5[n0 + ns*16 + l15];
    float mx = -1e30f, sum = 0.f;
#pragma unroll
    for (int ms = 0; ms < 2; ms++){
      float* a = (float*)&acc[ms][ns];
#pragma unroll
      for (int r = 0; r < 4; r++){
        float v = a[r] + bv; v = fmaxf(v, 0.2f*v);
        mx = fmaxf(mx, v); sum += v;
      }
    }
    for (int s = 16; s < 64; s <<= 1){
      mx = fmaxf(mx, __shfl_xor(mx, s));
      sum += __shfl_xor(sum, s);
    }
    if (quad == 0){ red[(w*8 + ns)*16 + l15] = mx; red[512 + (w*8 + ns)*16 + l15] = sum; }
  }
  __syncthreads();
  if (tid < 128){
    int ns = tid >> 4, ci = tid & 15;
    float mx = -1e30f, sum = 0.f;
#pragma unroll
    for (int w2 = 0; w2 < 4; w2++){
      mx = fmaxf(mx, red[(w2*8 + ns)*16 + ci]);
      sum += red[512 + (w2*8 + ns)*16 + ci];
    }
    pmax[(size_t)blockIdx.y*1024 + n0 + tid] = mx;
    psum[(size_t)blockIdx.y*1024 + n0 + tid] = sum;
  }
}

// ---------------- FC1: 2048->512, pool fused (max/mean over 8 chunks) ----------------
__global__ __launch_bounds__(256) void k_fc1(const float* __restrict__ pmax, const float* __restrict__ psum,
                                             const float* __restrict__ wl1, const float* __restrict__ bn6,
                                             float* __restrict__ h1){
  __shared__ float pS[2048];
  const int b = blockIdx.y, t = threadIdx.x;
  for (int f = t; f < 512; f += 256){
    float4 r;
    if (f < 256){
      r = ld4(pmax + (size_t)(b*8)*1024 + f*4);
#pragma unroll
      for (int ch = 1; ch < 8; ch++) max4(r, ld4(pmax + (size_t)(b*8+ch)*1024 + f*4));
    } else {
      int o = (f-256)*4;
      r = ld4(psum + (size_t)(b*8)*1024 + o);
#pragma unroll
      for (int ch = 1; ch < 8; ch++){
        float4 s = ld4(psum + (size_t)(b*8+ch)*1024 + o);
        r.x += s.x; r.y += s.y; r.z += s.z; r.w += s.w;
      }
      r.x *= (1.f/1024.f); r.y *= (1.f/1024.f); r.z *= (1.f/1024.f); r.w *= (1.f/1024.f);
    }
    ((float4*)pS)[f] = r;
  }
  __syncthreads();
  const int ol = t >> 4, ch = t & 15;
  const int o = blockIdx.x*16 + ol;
  const float* wr = wl1 + (size_t)o*2048;
  float acc = 0.f;
#pragma unroll
  for (int j = 0; j < 32; j++){
    int c = ch*4 + j*64;
    float4 wv = ld4(wr + c);
    acc += pS[c]*wv.x + pS[c+1]*wv.y + pS[c+2]*wv.z + pS[c+3]*wv.w;
  }
#pragma unroll
  for (int s = 1; s < 16; s <<= 1) acc += __shfl_xor(acc, s);
  if (ch == 0){
    float s = bn6[o] * rsqrtf(bn6[3*512+o] + BNEPS);
    float y = (acc - bn6[2*512+o])*s + bn6[512+o];
    h1[(size_t)b*512 + o] = fmaxf(y, 0.2f*y);
  }
}

// ---------------- FC2: 512->256 ----------------
__global__ __launch_bounds__(256) void k_fc2(const float* __restrict__ h1,
                                             const float* __restrict__ wl2, const float* __restrict__ bn7,
                                             float* __restrict__ h2){
  __shared__ float hS[512];
  const int b = blockIdx.y, t = threadIdx.x;
  if (t < 128) ((float4*)hS)[t] = ((const float4*)(h1 + (size_t)b*512))[t];
  __syncthreads();
  const int ol = t >> 4, ch = t & 15;
  const int o = blockIdx.x*16 + ol;
  const float* wr = wl2 + (size_t)o*512;
  float acc = 0.f;
#pragma unroll
  for (int j = 0; j < 8; j++){
    int c = ch*4 + j*64;
    float4 wv = ld4(wr + c);
    acc += hS[c]*wv.x + hS[c+1]*wv.y + hS[c+2]*wv.z + hS[c+3]*wv.w;
  }
#pragma unroll
  for (int s = 1; s < 16; s <<= 1) acc += __shfl_xor(acc, s);
  if (ch == 0){
    float s = bn7[o] * rsqrtf(bn7[3*256+o] + BNEPS);
    float y = (acc - bn7[2*256+o])*s + bn7[256+o];
    h2[(size_t)b*256 + o] = fmaxf(y, 0.2f*y);
  }
}

// ---------------- FC3: 256->40 ----------------
__global__ __launch_bounds__(64) void k_fc3(const float* __restrict__ h2,
                                            const float* __restrict__ wl3, const float* __restrict__ bl3,
                                            float* __restrict__ out){
  const int o = blockIdx.x, b = blockIdx.y, lane = threadIdx.x;
  float4 wv = ld4(wl3 + (size_t)o*256 + lane*4);
  float4 hv = ld4(h2 + (size_t)b*256 + lane*4);
  float acc = hv.x*wv.x + hv.y*wv.y + hv.z*wv.z + hv.w*wv.w;
#pragma unroll
  for (int s = 1; s < 64; s <<= 1) acc += __shfl_xor(acc, s);
  if (lane == 0) out[(size_t)b*40 + o] = acc + bl3[o];
}

extern "C" void kernel_launch(void* const* d_in, const int* in_sizes, int n_in,
                              void* d_out, int out_size, void* d_ws, size_t ws_size,
                              hipStream_t stream) {
  (void)in_sizes; (void)n_in; (void)out_size; (void)ws_size;
  const float* x   = (const float*)d_in[0];
  const float* w1  = (const float*)d_in[1];
  const float* bn1 = (const float*)d_in[2];
  const float* w2  = (const float*)d_in[3];
  const float* bn2 = (const float*)d_in[4];
  const float* w3  = (const float*)d_in[5];
  const float* bn3 = (const float*)d_in[6];
  const float* w4  = (const float*)d_in[7];
  const float* bn4 = (const float*)d_in[8];
  const float* w5  = (const float*)d_in[9];
  const float* bn5 = (const float*)d_in[10];
  const float* wl1 = (const float*)d_in[11];
  const float* bn6 = (const float*)d_in[12];
  const float* wl2 = (const float*)d_in[13];
  const float* bn7 = (const float*)d_in[14];
  const float* wl3 = (const float*)d_in[15];
  const float* bl3 = (const float*)d_in[16];
  float* out = (float*)d_out;

  float* ws    = (float*)d_ws;
  float* xt    = ws;                          // 65536
  float* sqb   = xt + 65536;                  // 16384
  int*   idxb  = (int*)(sqb + 16384);         // 327680 ints
  float* pd    = (float*)(idxb + 327680);     // 16777216 (Z aliases, used after topk)
  float* h     = pd + 16777216;               // 4194304 (fp32 acts, stride 256)
  float* wlT1  = h + 4194304;                 // 256
  float* dT1   = wlT1 + 256;                  // 256
  float* bias1 = dT1 + 256;                   // 64
  float* bias2 = bias1 + 64;                  // 64
  float* bias3 = bias2 + 64;                  // 128
  float* bias4 = bias3 + 128;                 // 256
  float* b5    = bias4 + 256;                 // 1024
  float* pmax  = b5 + 1024;                   // 131072
  float* psum  = pmax + 131072;               // 131072
  float* pool  = psum + 131072;               // 32768 (unused; layout kept)
  float* h1b   = pool + 32768;                // 8192
  float* h2b   = h1b + 8192;                  // 4096
  unsigned short* hb   = (unsigned short*)(h2b + 4096);    // 16384*512 bf16
  unsigned short* wlB2 = hb + (size_t)16384*512;            // 4096 (dB2 contiguous after)
  unsigned short* dB2  = wlB2 + 4096;
  unsigned short* wlB3 = dB2 + 4096;                        // 8192 (dB3 contiguous)
  unsigned short* dB3  = wlB3 + 8192;
  unsigned short* wlB4 = dB3 + 8192;                        // 32768 (dB4 contiguous)
  unsigned short* dB4  = wlB4 + 32768;
  unsigned short* w5b  = dB4 + 32768;                       // 524288
  float* Z = pd;

  k_transpose<<<64, 256, 0, stream>>>(x, xt, sqb);
  k_prep_all<<<2225, 256, 0, stream>>>(w1, bn1, w2, bn2, w3, bn3, w4, bn4, w5, bn5,
                                       wlT1, dT1, bias1, wlB2, dB2, bias2,
                                       wlB3, dB3, bias3, wlB4, dB4, bias4, w5b, b5);

  // pd LDS: max(staging 2*64*(CT+4)*4, transpose 64*68*4 = 17408)
  const size_t PD_LDS64 = 34816;   // CT=64 staging dominates
  const size_t PD_LDS4  = 17408;   // CT=4: transpose buffer dominates

  // ---- L1 (Cin=4 -> Cout=64) ----
  k_pd<<<dim3(136,16), 256, PD_LDS4, stream>>>(xt, 4, 4, 4, 0, sqb, pd);
  k_topk<<<2048, 256, 0, stream>>>(pd, idxb);
  k_uv1<<<2048, 256, 0, stream>>>(xt, wlT1, dT1, Z);
  k_gmax<64,16,true><<<1024, 256, 0, stream>>>(Z, bias1, idxb, h, hb);

  // ---- L2 (64 -> 64) ----
  k_sq<<<64, 256, 0, stream>>>(h, 256, 64, sqb);
  k_pd<<<dim3(136,16), 256, PD_LDS64, stream>>>(h, 256, 64, 64, 4, sqb, pd);
  k_topk<<<2048, 256, 0, stream>>>(pd, idxb);
  k_uv<64><<<dim3(1,128), 256, 0, stream>>>(hb, wlB2, Z, 128);
  k_gmax<64,16,true><<<1024, 256, 0, stream>>>(Z, bias2, idxb, h + 64, hb + 64);

  // ---- L3 (64 -> 128) ----
  k_sq<<<64, 256, 0, stream>>>(h + 64, 256, 64, sqb);
  k_pd<<<dim3(136,16), 256, PD_LDS64, stream>>>(h + 64, 256, 64, 64, 4, sqb, pd);
  k_topk<<<2048, 256, 0, stream>>>(pd, idxb);
  k_uv<64><<<dim3(2,128), 256, 0, stream>>>(hb + 64, wlB3, Z, 256);
  k_gmax<128,8,true><<<2048, 256, 0, stream>>>(Z, bias3, idxb, h + 128, hb + 128);

  // ---- L4 (128 -> 256; bf16 out only) ----
  k_sq<<<64, 256, 0, stream>>>(h + 128, 256, 128, sqb);
  k_pd<<<dim3(136,16), 256, PD_LDS64, stream>>>(h + 128, 256, 128, 64, 4, sqb, pd);
  k_topk<<<2048, 256, 0, stream>>>(pd, idxb);
  k_uv<128><<<dim3(4,128), 256, 0, stream>>>(hb + 128, wlB4, Z, 512);
  k_gmax<256,4,false><<<4096, 256, 0, stream>>>(Z, bias4, idxb, nullptr, hb + 256);

  // ---- conv5 + FC head (pool fused into fc1) ----
  k_conv5m<<<dim3(8,128), 256, 0, stream>>>(hb, w5b, b5, pmax, psum);
  k_fc1<<<dim3(32,16), 256, 0, stream>>>(pmax, psum, wl1, bn6, h1b);
  k_fc2<<<dim3(16,16), 256, 0, stream>>>(h1b, wl2, bn7, h2b);
  k_fc3<<<dim3(40,16), 64, 0, stream>>>(h2b, wl3, bl3, out);
}